// Round 9
// baseline (155.404 us; speedup 1.0000x reference)
//
#include <hip/hip_runtime.h>
#include <math.h>

#define L_LEN 16384
#define M_LEN 8192
#define KT_LEN 4096
#define BB 32
#define NTPL 50
#define SPEC_STRIDE 8224   // complex slots per signal (>= 8193)
#define NSIG 166           // 64 x-signals + 2 w-signals + 100 templates
#define NTI 512            // inv block (radix 2,16,16,16 ladder)
#define PI_F 3.14159265358979323846f
#define R2_F 0.70710678118654752f
// W_8192^1 = e^{-2pi i/8192}: cos(pi/4096), sin(pi/4096)
#define CW1 0.99999970586288223f
#define SW1 7.6699031874270453e-4f

typedef float cf2 __attribute__((ext_vector_type(2)));

// Lessons encoded in this structure:
//  R5: scattered per-lane twiddle loads stall VMEM -> power chain from 1 load.
//  R6: XOR swizzle + cf2 packed math + algebraic per-stage indices = best layout.
//  R7: +1-per-32 pad layout TRIPLES bank conflicts vs XOR swizzle (FFT tiles).
//  R8: __shfl_xor compiles to ds_bpermute (LDS pipe!) - shfl stage fusion loses.
//  R9: inv is not occupancy-bound (radix-8/1024t: occ 2x, dur +9%).
//  R10/R11: VOP3P pk asm for cmul + product pass: VALU 74->58%, inv 69->65us.
//  R12: head LDS-staged: neutral.
//  R13 REVERTED: pair-based fwd untangle broke global write coalescing (+4.7us).
//  R14 REVERTED: DPP-fused radix-2 cost +8.4us (s_nop wait-states serialize).
//  R15: radix-2-first + read-only last stage: VALU 58.6->53.5%, dur FLAT.
//  R16: X*V hoisted (50x redundancy removed, L2 -28%): dur FLAT again.
//      Three nulls => inv pinned at a barrier-latency floor at 16 waves/CU.
//  R17 (this round): fwd was the hidden residual suspect - it ran 1024-thr
//      1-block/CU = 2 waves/SIMD (worst latency hiding), 182 blocks < 256 CUs.
//      Split each FFT into TWO independent 4096-pt half-blocks (DIF radix-2
//      fused into the load): 256 thr, 32KB LDS -> 4-5 blocks/CU resident,
//      3 radix-16 stages (verified inv half-ladder index formulas reused),
//      grid 396. Untangle pairs (f,8192-f) share parity -> stay in-block;
//      out writes stride-2 (half-coalesced, NOT R13's scatter).

// Packed complex multiply: 2 VOP3P instructions.
__device__ __forceinline__ cf2 cmul(cf2 a, cf2 b) {
    cf2 t, d;
    asm("v_pk_mul_f32 %0, %1, %2 op_sel:[0,0] op_sel_hi:[0,1]"
        : "=v"(t) : "v"(a), "v"(b));
    asm("v_pk_fma_f32 %0, %1, %2, %3 op_sel:[1,1,0] op_sel_hi:[1,0,1] neg_lo:[0,1,0]"
        : "=v"(d) : "v"(a), "v"(b), "v"(t));
    return d;
}
// a * conj(b): re = ax*bx + ay*by, im = ay*bx - ax*by. 2 VOP3P insts.
__device__ __forceinline__ cf2 cmulc(cf2 a, cf2 b) {
    cf2 t, d;
    asm("v_pk_mul_f32 %0, %1, %2 op_sel:[0,0] op_sel_hi:[0,1] neg_hi:[0,1]"
        : "=v"(t) : "v"(a), "v"(b));   // {ax*bx, -ax*by}
    asm("v_pk_fma_f32 %0, %1, %2, %3 op_sel:[1,1,0] op_sel_hi:[1,0,1]"
        : "=v"(d) : "v"(a), "v"(b), "v"(t));
    return d;
}
// conj(a) * b: re = ax*bx + ay*by, im = ax*by - ay*bx. 2 VOP3P insts.
__device__ __forceinline__ cf2 cmulca(cf2 a, cf2 b) {
    cf2 t, d;
    asm("v_pk_mul_f32 %0, %1, %2 op_sel:[0,0] op_sel_hi:[0,1]"
        : "=v"(t) : "v"(a), "v"(b));   // {ax*bx, ax*by}
    asm("v_pk_fma_f32 %0, %1, %2, %3 op_sel:[1,1,0] op_sel_hi:[1,0,1] neg_hi:[1,0,0]"
        : "=v"(d) : "v"(a), "v"(b), "v"(t));
    return d;
}
// {ax+bx, ay-by}
__device__ __forceinline__ cf2 pk_addch(cf2 a, cf2 b) {
    cf2 d;
    asm("v_pk_add_f32 %0, %1, %2 neg_hi:[0,1]" : "=v"(d) : "v"(a), "v"(b));
    return d;
}
// {ax-bx, ay+by}
__device__ __forceinline__ cf2 pk_subcl(cf2 a, cf2 b) {
    cf2 d;
    asm("v_pk_add_f32 %0, %1, %2 neg_lo:[0,1]" : "=v"(d) : "v"(a), "v"(b));
    return d;
}
// {s.x - r.y, s.y + r.x}  (= s + i*r)
__device__ __forceinline__ cf2 pk_compose1(cf2 s, cf2 r) {
    cf2 d;
    asm("v_pk_add_f32 %0, %1, %2 op_sel:[0,1] op_sel_hi:[0,0] neg_lo:[0,1]"
        : "=v"(d) : "v"(s), "v"(r));
    return d;
}
// {s.x + r.y, r.x - s.y}  (= conj(s - i*r))
__device__ __forceinline__ cf2 pk_compose2(cf2 s, cf2 r) {
    cf2 d;
    asm("v_pk_add_f32 %0, %1, %2 op_sel:[0,1] op_sel_hi:[0,0] neg_hi:[1,0]"
        : "=v"(d) : "v"(s), "v"(r));
    return d;
}
template<int SIGN>
__device__ __forceinline__ cf2 rot90(cf2 z) {
    return (SIGN < 0) ? (cf2){z.y, -z.x} : (cf2){-z.y, z.x};
}
template<int SIGN>
__device__ __forceinline__ cf2 ldT(const cf2* __restrict__ T, int idx) {
    cf2 t = T[idx];
    if (SIGN > 0) t.y = -t.y;
    return t;
}

// LDS bank swizzle. Even XOR keeps float4 pair adjacency; involution.
__device__ __forceinline__ int swz(int i) { return i ^ (((i >> 5) & 15) << 1); }

// Digit reversal for a 16,16,16 DIF ladder on 4096 points.
__device__ __forceinline__ int pos4(int f) {
    return ((f & 15) << 8) | (f & 0xF0) | ((f >> 8) & 15);
}

// ---------------- radix-16 pieces ----------------
template<int SIGN>
__device__ __forceinline__ void dft16(cf2 x[16]) {
    const float S = (SIGN < 0) ? -1.f : 1.f;
    const cf2 w1 = {0.9238795325112867f, S * 0.3826834323650898f};
    const cf2 w2 = {0.7071067811865476f, S * 0.7071067811865476f};
    const cf2 w3 = {0.3826834323650898f, S * 0.9238795325112867f};
    cf2 v[16];
    #pragma unroll
    for (int n1 = 0; n1 < 4; ++n1) {
        cf2 a0 = x[n1], a1 = x[n1+4], a2 = x[n1+8], a3 = x[n1+12];
        cf2 t0 = a0 + a2, t2 = a0 - a2;
        cf2 t1 = a1 + a3, t3 = rot90<SIGN>(a1 - a3);
        cf2 u0 = t0 + t1, u1 = t2 + t3;
        cf2 u2 = t0 - t1, u3 = t2 - t3;
        if (n1 == 1) { u1 = cmul(u1, w1); u2 = cmul(u2, w2); u3 = cmul(u3, w3); }
        else if (n1 == 2) { u1 = cmul(u1, w2); u2 = rot90<SIGN>(u2);
                            u3 = rot90<SIGN>(cmul(u3, w2)); }
        else if (n1 == 3) { u1 = cmul(u1, w3); u2 = rot90<SIGN>(cmul(u2, w2));
                            u3 = -cmul(u3, w1); }
        v[0*4+n1] = u0; v[1*4+n1] = u1; v[2*4+n1] = u2; v[3*4+n1] = u3;
    }
    #pragma unroll
    for (int r = 0; r < 4; ++r) {
        cf2 a0 = v[r*4+0], a1 = v[r*4+1], a2 = v[r*4+2], a3 = v[r*4+3];
        cf2 t0 = a0 + a2, t2 = a0 - a2;
        cf2 t1 = a1 + a3, t3 = rot90<SIGN>(a1 - a3);
        x[r]    = t0 + t1; x[r+4]  = t2 + t3;
        x[r+8]  = t0 - t1; x[r+12] = t2 - t3;
    }
}

template<int SIGN>
__device__ __forceinline__ void butterfly16(cf2* A, const int idx[16], cf2 w1) {
    cf2 x[16];
    #pragma unroll
    for (int n = 0; n < 16; ++n) x[n] = A[idx[n]];
    dft16<SIGN>(x);
    A[idx[0]] = x[0];
    A[idx[1]] = cmul(x[1], w1);
    const cf2 w2 = cmul(w1, w1);
    A[idx[2]] = cmul(x[2], w2);
    const cf2 w3 = cmul(w1, w2);
    A[idx[3]] = cmul(x[3], w3);
    const cf2 w4 = cmul(w2, w2);
    A[idx[4]] = cmul(x[4], w4);
    A[idx[5]] = cmul(x[5], cmul(w1, w4));
    A[idx[6]] = cmul(x[6], cmul(w2, w4));
    A[idx[7]] = cmul(x[7], cmul(w3, w4));
    const cf2 w8 = cmul(w4, w4);
    A[idx[8]]  = cmul(x[8],  w8);
    A[idx[9]]  = cmul(x[9],  cmul(w1, w8));
    A[idx[10]] = cmul(x[10], cmul(w2, w8));
    A[idx[11]] = cmul(x[11], cmul(w3, w8));
    const cf2 w12 = cmul(w4, w8);
    A[idx[12]] = cmul(x[12], w12);
    A[idx[13]] = cmul(x[13], cmul(w1, w12));
    A[idx[14]] = cmul(x[14], cmul(w2, w12));
    A[idx[15]] = cmul(x[15], cmul(w3, w12));
}

// ---------------------------------------------------------------------------
// Kernel 1 (R17): forward real FFT via TWO independent 4096-pt half-blocks.
// hb = blockIdx.x: hb < 2*NSIG -> sig = hb>>1, half = hb&1.
//   half 0: Z[2m]   = FFT4096{ c[k] + c[k+4096] }[m]
//   half 1: Z[2m+1] = FFT4096{ (c[k] - c[k+4096]) * W_8192^k }[m]
// 256 threads, 32 KB LDS, 3 radix-16 stages (stage 3 twiddle-free), then
// the Hermitian untangle for f of this half's parity (pairs f/8192-f share
// parity -> in-block). Blocks [2*NSIG, 2*NSIG+64) write the twiddle table.
// W blocks (sig 64/65) fold in V(f) = conj(W(f)) * e^{-i pi k/8192}.
// ---------------------------------------------------------------------------
__global__ __launch_bounds__(256, 4)
void fwd_fft_kernel(const float* __restrict__ xi, const float* __restrict__ w,
                    const float* __restrict__ tmpl, cf2* __restrict__ Tw,
                    cf2* __restrict__ spec) {
    __shared__ __attribute__((aligned(16))) cf2 A[4096];   // 32 KB
    const int hb = blockIdx.x;
    const int tid = threadIdx.x;

    if (hb >= 2*NSIG) {   // twiddle writer: T[k] = e^{-2 pi i k / 16384}
        const int k = (hb - 2*NSIG) * 256 + tid;
        const int quad = k >> 12, mm = k & 4095;
        float s, c; __sincosf(PI_F * (float)mm / 8192.f, &s, &c);
        cf2 v;   // (cos th, -sin th), th = pi k/8192 = quad*pi/2 + t
        if      (quad == 0) v = (cf2){ c, -s};
        else if (quad == 1) v = (cf2){-s, -c};
        else if (quad == 2) v = (cf2){-c,  s};
        else                v = (cf2){ s,  c};
        Tw[k] = v;
        return;
    }

    const int sig = hb >> 1, half = hb & 1;
    const float* src;
    int nre;
    if (sig < 64)      { src = xi   + sig * L_LEN;         nre = L_LEN; }
    else if (sig < 66) { src = w    + (sig - 64) * L_LEN;  nre = L_LEN; }
    else               { src = tmpl + (sig - 66) * KT_LEN; nre = KT_LEN; }
    const bool isW = (sig >= 64 && sig < 66);
    const int nf4 = nre >> 2;                 // float4 count of source
    const float4* s4 = (const float4*)src;

    // Load + fused radix-2 (DIF). j = complex-pair float4 index in [0,2048).
    // c-pair (c[2j], c[2j+1]) = s4[j]; partner (c[2j+4096], ...) = s4[j+2048].
    const cf2 w1c = (cf2){CW1, -SW1};         // W_8192^1
    #pragma unroll
    for (int mm = 0; mm < 8; ++mm) {
        const int j = tid + 256*mm;
        float4 a = (j < nf4)        ? s4[j]        : make_float4(0.f,0.f,0.f,0.f);
        float4 b = (j + 2048 < nf4) ? s4[j + 2048] : make_float4(0.f,0.f,0.f,0.f);
        cf2 c0 = (cf2){a.x, a.y}, c1 = (cf2){a.z, a.w};
        cf2 d0 = (cf2){b.x, b.y}, d1 = (cf2){b.z, b.w};
        cf2 h0, h1;
        if (half == 0) { h0 = c0 + d0; h1 = c1 + d1; }
        else {
            float sn, cs; __sincosf(-PI_F * (float)j / 2048.f, &sn, &cs);
            cf2 wk = (cf2){cs, sn};           // W_8192^{2j}
            h0 = cmul(c0 - d0, wk);
            h1 = cmul(c1 - d1, cmul(wk, w1c));
        }
        const int g = j ^ ((j >> 4) & 15);    // float4 LDS index (swz(2j)/2)
        ((float4*)A)[g] = make_float4(h0.x, h0.y, h1.x, h1.y);
    }
    __syncthreads();

    {   // stage 1: stride 256, w1 = W_4096^tid
        const int jx = tid ^ (((tid >> 5) & 7) << 1);
        int idx[16];
        #pragma unroll
        for (int n = 0; n < 16; ++n) idx[n] = (jx ^ ((n & 1) << 4)) + 256*n;
        float sn, cs; __sincosf(-PI_F * (float)tid / 2048.f, &sn, &cs);
        butterfly16<-1>(A, idx, (cf2){cs, sn});
    }
    __syncthreads();
    {   // stage 2: stride 16, w1 = W_256^j
        const int q = tid >> 4, j = tid & 15;
        const int base = q << 8, qb = q & 1;
        int idx[16];
        #pragma unroll
        for (int n = 0; n < 16; ++n)
            idx[n] = base + 16*(n ^ qb) + (j ^ (((n >> 1) & 7) << 1));
        float sn, cs; __sincosf(-PI_F * (float)j / 128.f, &sn, &cs);
        butterfly16<-1>(A, idx, (cf2){cs, sn});
    }
    __syncthreads();
    {   // stage 3: stride 1, twiddle-free dft16, b128 in/out.
        const int bb = 16 * (tid ^ ((tid >> 4) & 1));
        const int m3 = ((tid >> 1) & 7) << 1;
        cf2 x[16];
        #pragma unroll
        for (int e = 0; e < 8; ++e) {
            float4 v = ((const float4*)A)[(bb + ((2*e) ^ m3)) >> 1];
            x[2*e]     = (cf2){v.x, v.y};
            x[2*e + 1] = (cf2){v.z, v.w};
        }
        dft16<-1>(x);
        #pragma unroll
        for (int e = 0; e < 8; ++e)
            ((float4*)A)[(bb + ((2*e) ^ m3)) >> 1] =
                make_float4(x[2*e].x, x[2*e].y, x[2*e+1].x, x[2*e+1].y);
    }
    __syncthreads();

    // Untangle this half's parity: f = 2m+half, partner 8192-f (same parity).
    // half 0: Za = Zt[m], Zb = Zt[(4096-m)&4095]
    // half 1: Za = Zb[m], Zb = Zb[4095-m]
    cf2* out = spec + (size_t)sig * SPEC_STRIDE;
    #pragma unroll
    for (int mm = 0; mm < 16; ++mm) {
        const int m = tid + 256*mm;
        const int mb = half ? (4095 - m) : ((4096 - m) & 4095);
        const int f = 2*m + half;
        cf2 Za = A[swz(pos4(m))];
        cf2 Zb = A[swz(pos4(mb))];
        cf2 E = (cf2){0.5f*(Za.x + Zb.x), 0.5f*(Za.y - Zb.y)};
        cf2 D = (cf2){Za.x - Zb.x, Za.y + Zb.y};
        cf2 O = (cf2){0.5f*D.y, -0.5f*D.x};
        float sn, cs;
        __sincosf(-PI_F * (float)f / 8192.f, &sn, &cs);
        cf2 val = E + (cf2){cs*O.x - sn*O.y, cs*O.y + sn*O.x};
        if (isW) {   // V(f) = conj(W(f)) * e^{-i pi k/8192}, k exact int mod
            const int k = (4094 * f) & (L_LEN - 1);
            float psn, pcs; __sincosf(-PI_F * (float)k / 8192.f, &psn, &pcs);
            val = cmul((cf2){val.x, -val.y}, (cf2){pcs, psn});
        }
        out[f] = val;
    }
    if (half == 0 && tid == 0) {   // f = 8192 from Z[0] = Zt[0] = A[0]
        cf2 Za = A[0];
        cf2 val = (cf2){Za.x - Za.y, 0.f};
        if (isW) {   // k(8192) = 8192 -> phase = (-1, 0)
            val = (cf2){-val.x, 0.f};
        }
        out[M_LEN] = val;
    }
}

// ---------------------------------------------------------------------------
// Kernel 1b (R16): XV[f] = X[f]*V[f], in-place into X's spec slots.
// One block per (b,c); V slots (64/65) read-only; no cross-block hazard.
// ---------------------------------------------------------------------------
__global__ __launch_bounds__(1024)
void xv_kernel(cf2* __restrict__ spec) {
    const int bc = blockIdx.x;          // 0..63 = b*2 + c
    cf2* Xs = spec + (size_t)bc * SPEC_STRIDE;
    const cf2* Vs = spec + (size_t)(64 + (bc & 1)) * SPEC_STRIDE;
    const int tid = threadIdx.x;
    float4* X4 = (float4*)Xs;
    const float4* V4 = (const float4*)Vs;
    #pragma unroll
    for (int m = 0; m < 4; ++m) {
        const int p = tid + 1024*m;     // float4 pair index < 4096
        float4 xv = X4[p], vv = V4[p];
        cf2 a = cmul((cf2){xv.x, xv.y}, (cf2){vv.x, vv.y});
        cf2 b = cmul((cf2){xv.z, xv.w}, (cf2){vv.z, vv.w});
        X4[p] = make_float4(a.x, a.y, b.x, b.y);
    }
    if (tid == 0) Xs[M_LEN] = cmul(Xs[M_LEN], Vs[M_LEN]);
}

// ---------------------------------------------------------------------------
// Kernel 2 (R15+R16): product (XV * conj(H)) + Hermitian pack + FIRST radix-2
// stage fused in registers (in-thread; no cross-lane). Then 16,16,16 stages
// on the two 4096-halves; stride-1 last stage (twiddle = 1) is read-only+max.
// Z' carries 2x (0.5 dropped) -> divide by 2*M*hh.
// ---------------------------------------------------------------------------
__global__ __launch_bounds__(NTI, 4)
void inv_fft_kernel(const cf2* __restrict__ spec, const cf2* __restrict__ T,
                    const float* __restrict__ hh, float* __restrict__ zarr) {
    __shared__ __attribute__((aligned(16))) cf2 A[M_LEN];   // 64 KB
    const int idx0 = blockIdx.x;
    const int c = idx0 & 1;
    const int n = (idx0 >> 1) % NTPL;
    const int b = idx0 / (2 * NTPL);
    const int tid = threadIdx.x;

    const cf2* Xs = spec + (size_t)(b*2 + c)      * SPEC_STRIDE;   // = XV
    const cf2* Hs = spec + (size_t)(66 + n*2 + c) * SPEC_STRIDE;
    const float4* X4 = (const float4*)Xs;
    const float4* H4 = (const float4*)Hs;
    const float4* T4 = (const float4*)T;

    #pragma unroll
    for (int m = 0; m < 2; ++m) {
        const int tp = tid + 512*m;
        const int f0 = 2*tp, f1 = f0 + 1;
        float4 xa = X4[tp],        ha = H4[tp];
        float4 xq = X4[tp + 2048], hq = H4[tp + 2048];
        cf2 PA0 = cmulc((cf2){xa.x, xa.y}, (cf2){ha.x, ha.y});
        cf2 PA1 = cmulc((cf2){xa.z, xa.w}, (cf2){ha.z, ha.w});
        cf2 QB0 = cmulc((cf2){xq.x, xq.y}, (cf2){hq.x, hq.y});
        cf2 QB1 = cmulc((cf2){xq.z, xq.w}, (cf2){hq.z, hq.w});
        cf2 PB0 = cmulc(Xs[4096 - f0], Hs[4096 - f0]);
        cf2 PB1 = cmulc(Xs[4096 - f1], Hs[4096 - f1]);
        cf2 QA0 = cmulc(Xs[8192 - f0], Hs[8192 - f0]);
        cf2 QA1 = cmulc(Xs[8192 - f1], Hs[8192 - f1]);
        float4 tf4 = T4[tp];            // T[f0], T[f1]
        float4 t2a = T4[2*tp];          // T[2f0] in .xy
        float4 t2b = T4[2*tp + 1];      // T[2f1] in .xy
        cf2 Tf0 = (cf2){tf4.x, tf4.y}, Tf1 = (cf2){tf4.z, tf4.w};
        cf2 T20 = (cf2){t2a.x, t2a.y}, T21 = (cf2){t2b.x, t2b.y};
        // --- f0 ---
        cf2 SpA0 = pk_addch(PA0, QA0), SmA0 = pk_subcl(PA0, QA0);
        cf2 RA0 = cmulca(Tf0, SmA0);
        cf2 ZA1_0 = pk_compose1(SpA0, RA0);     // Z'[f0]
        cf2 ZA2_0 = pk_compose2(SpA0, RA0);     // Z'[8192-f0]
        cf2 tB0 = (cf2){-Tf0.y, -Tf0.x};        // T[4096-f0]
        cf2 SpB0 = pk_addch(PB0, QB0), SmB0 = pk_subcl(PB0, QB0);
        cf2 RB0 = cmulca(tB0, SmB0);
        cf2 ZB1_0 = pk_compose1(SpB0, RB0);     // Z'[4096-f0]
        cf2 ZB2_0 = pk_compose2(SpB0, RB0);     // Z'[4096+f0]
        cf2 top0 = ZA1_0 + ZB2_0;
        cf2 bot0 = cmulca(T20, ZA1_0 - ZB2_0);
        // --- f1 ---
        cf2 SpA1 = pk_addch(PA1, QA1), SmA1 = pk_subcl(PA1, QA1);
        cf2 RA1 = cmulca(Tf1, SmA1);
        cf2 ZA1_1 = pk_compose1(SpA1, RA1);
        cf2 ZA2_1 = pk_compose2(SpA1, RA1);
        cf2 tB1 = (cf2){-Tf1.y, -Tf1.x};
        cf2 SpB1 = pk_addch(PB1, QB1), SmB1 = pk_subcl(PB1, QB1);
        cf2 RB1 = cmulca(tB1, SmB1);
        cf2 ZB1_1 = pk_compose1(SpB1, RB1);
        cf2 ZB2_1 = pk_compose2(SpB1, RB1);
        cf2 top1 = ZA1_1 + ZB2_1;
        cf2 bot1 = cmulca(T21, ZA1_1 - ZB2_1);
        // coalesced swizzled float4 writes for the fwd side
        const int gt = tp ^ ((tp >> 4) & 15);
        ((float4*)A)[gt]        = make_float4(top0.x, top0.y, top1.x, top1.y);
        ((float4*)A)[2048 + gt] = make_float4(bot0.x, bot0.y, bot1.x, bot1.y);
        // rev-side butterflies (skip f0 == 0: its pair (4096,8192) is invalid;
        // the fwd butterfly above already used the correct self-paired Z'[4096])
        if (tp > 0) {
            cf2 tr0 = ZB1_0 + ZA2_0;
            cf2 dr0 = cmul(ZB1_0 - ZA2_0, T20);
            A[swz(4096 - f0)] = tr0;
            A[swz(8192 - f0)] = -dr0;
        }
        cf2 tr1 = ZB1_1 + ZA2_1;
        cf2 dr1 = cmul(ZB1_1 - ZA2_1, T21);
        A[swz(4096 - f1)] = tr1;
        A[swz(8192 - f1)] = -dr1;
    }
    if (tid == 0) {   // f = 2048 butterfly (2048, 6144), Wi^2048 = +i
        cf2 P = cmulc(Xs[2048], Hs[2048]);
        cf2 Q = cmulc(Xs[6144], Hs[6144]);
        cf2 Tc = (cf2){R2_F, -R2_F};           // T[2048]
        cf2 Sp = pk_addch(P, Q), Sm = pk_subcl(P, Q);
        cf2 R = cmulca(Tc, Sm);
        cf2 Z1 = pk_compose1(Sp, R), Z2 = pk_compose2(Sp, R);
        cf2 d = Z1 - Z2;
        A[swz(2048)] = Z1 + Z2;
        A[swz(6144)] = (cf2){-d.y, d.x};
    }
    __syncthreads();

    {   // stage 1 of the 4096-halves: stride 256, w1 = conj(T[4j])
        const int h = tid >> 8, j = tid & 255;
        const int Hb = h << 12;
        const int jx = j ^ (((j >> 5) & 7) << 1);
        int idx[16];
        #pragma unroll
        for (int nn = 0; nn < 16; ++nn)
            idx[nn] = Hb + 256*nn + (jx ^ ((nn & 1) << 4));
        butterfly16<+1>(A, idx, ldT<+1>(T, 4*j));
    }
    __syncthreads();
    {   // stage 2: stride 16, w1 = conj(T[64j])
        const int h = tid >> 8, q = (tid >> 4) & 15, j = tid & 15;
        const int base = (h << 12) + (q << 8);
        const int qb = q & 1;
        int idx[16];
        #pragma unroll
        for (int nn = 0; nn < 16; ++nn)
            idx[nn] = base + 16*(nn ^ qb) + (j ^ (((nn >> 1) & 7) << 1));
        butterfly16<+1>(A, idx, ldT<+1>(T, 64*j));
    }
    __syncthreads();

    // stage 3: stride 1, twiddle = W_16^0 = 1 -> read-only dft16 + max.
    float mx = -INFINITY;
    {
        const int bb = 16 * (tid ^ ((tid >> 4) & 1));
        const int m3 = ((tid >> 1) & 7) << 1;
        cf2 x[16];
        #pragma unroll
        for (int e = 0; e < 8; ++e) {
            float4 v = ((const float4*)A)[(bb + ((2*e) ^ m3)) >> 1];
            x[2*e]     = (cf2){v.x, v.y};
            x[2*e + 1] = (cf2){v.z, v.w};
        }
        dft16<+1>(x);
        #pragma unroll
        for (int nn = 0; nn < 16; ++nn)
            mx = fmaxf(mx, fmaxf(x[nn].x, x[nn].y));
    }
    __syncthreads();   // all stage-3 reads done before reusing A as scratch
    for (int off = 32; off > 0; off >>= 1)
        mx = fmaxf(mx, __shfl_xor(mx, off));
    const int lane = tid & 63, wv = tid >> 6;   // 8 waves
    float* redf = (float*)A;
    if (lane == 0) redf[wv] = mx;
    __syncthreads();
    if (tid == 0) {
        float mm = redf[0];
        for (int i = 1; i < NTI/64; ++i) mm = fmaxf(mm, redf[i]);
        zarr[(b*2 + c)*NTPL + n] = mm / (2.f * (float)M_LEN * hh[n*2 + c]);
    }
}

// ---------------------------------------------------------------------------
// Kernel 3: tiny CNN/MLP head. One block per batch element.
// R12: all weights staged in LDS (coalesced), all MAC loops unrolled over
// LDS reads, fc1 parallelized 32 outputs x 8 lanes + shfl_xor tree.
// ---------------------------------------------------------------------------
#define W1_OFF 0        // 16x6 = 96
#define B1_OFF 96       // 16
#define W2_OFF 112      // 32x48 = 1536
#define B2_OFF 1648     // 32
#define W3_OFF 1680     // 32x132 (padded from 128) = 4224
#define B3_OFF 5904     // 32
#define W4_OFF 5936     // 2x32 = 64
#define B4_OFF 6000     // 2
#define WSM_SZ 6002

__global__ __launch_bounds__(256)
void head_kernel(const float* __restrict__ zarr,
                 const float* __restrict__ W1, const float* __restrict__ b1,
                 const float* __restrict__ W2, const float* __restrict__ b2,
                 const float* __restrict__ W3, const float* __restrict__ b3,
                 const float* __restrict__ W4, const float* __restrict__ b4,
                 float* __restrict__ out) {
    __shared__ float wsm[WSM_SZ];
    __shared__ float zl[2*NTPL];
    __shared__ float s1[16*48];
    __shared__ float p1[16*16];
    __shared__ float s2[32*14];
    __shared__ float hflat[128];
    __shared__ float h1[32];
    const int b = blockIdx.x, tid = threadIdx.x;

    for (int i = tid; i < 96;   i += 256) wsm[W1_OFF + i] = W1[i];
    if (tid < 16)                         wsm[B1_OFF + tid] = b1[tid];
    for (int i = tid; i < 1536; i += 256) wsm[W2_OFF + i] = W2[i];
    if (tid < 32)                         wsm[B2_OFF + tid] = b2[tid];
    for (int i = tid; i < 4096; i += 256)
        wsm[W3_OFF + (i >> 7)*132 + (i & 127)] = W3[i];
    if (tid < 32)                         wsm[B3_OFF + tid] = b3[tid];
    if (tid < 64)                         wsm[W4_OFF + tid] = W4[tid];
    if (tid < 2)                          wsm[B4_OFF + tid] = b4[tid];
    for (int i = tid; i < 2*NTPL; i += 256) zl[i] = zarr[b*2*NTPL + i];
    __syncthreads();

    for (int i = tid; i < 16*48; i += 256) {
        const int o = i / 48, t = i % 48;
        float acc = wsm[B1_OFF + o];
        #pragma unroll
        for (int cc = 0; cc < 2; ++cc)
            #pragma unroll
            for (int k = 0; k < 3; ++k)
                acc += zl[cc*NTPL + t + k] * wsm[W1_OFF + o*6 + cc*3 + k];
        s1[i] = 1.f / (1.f + __expf(-acc));
    }
    __syncthreads();
    for (int i = tid; i < 16*16; i += 256) {
        const int o = i / 16, u = i % 16;
        p1[i] = fmaxf(fmaxf(s1[o*48 + 3*u], s1[o*48 + 3*u+1]), s1[o*48 + 3*u+2]);
    }
    __syncthreads();
    for (int i = tid; i < 32*14; i += 256) {
        const int o = i / 14, t = i % 14;
        float acc = wsm[B2_OFF + o];
        #pragma unroll
        for (int cc = 0; cc < 16; ++cc)
            #pragma unroll
            for (int k = 0; k < 3; ++k)
                acc += p1[cc*16 + t + k] * wsm[W2_OFF + o*48 + cc*3 + k];
        s2[o*14 + t] = 1.f / (1.f + __expf(-acc));
    }
    __syncthreads();
    for (int i = tid; i < 128; i += 256) {
        const int o = i / 4, u = i % 4;
        hflat[i] = fmaxf(fmaxf(s2[o*14 + 3*u], s2[o*14 + 3*u+1]), s2[o*14 + 3*u+2]);
    }
    __syncthreads();
    {
        const int o = tid >> 3, lg = tid & 7;
        float acc = 0.f;
        #pragma unroll
        for (int k = 0; k < 16; ++k)
            acc += hflat[lg + 8*k] * wsm[W3_OFF + o*132 + lg + 8*k];
        acc += __shfl_xor(acc, 1);
        acc += __shfl_xor(acc, 2);
        acc += __shfl_xor(acc, 4);
        if (lg == 0) h1[o] = fmaxf(acc + wsm[B3_OFF + o], 0.f);
    }
    __syncthreads();
    if (tid < 64) {
        const int o = tid >> 5, j = tid & 31;
        float p = h1[j] * wsm[W4_OFF + o*32 + j];
        p += __shfl_xor(p, 1);
        p += __shfl_xor(p, 2);
        p += __shfl_xor(p, 4);
        p += __shfl_xor(p, 8);
        p += __shfl_xor(p, 16);
        if (j == 0) out[b*2 + o] = p + wsm[B4_OFF + o];
    }
}

extern "C" void kernel_launch(void* const* d_in, const int* in_sizes, int n_in,
                              void* d_out, int out_size, void* d_ws, size_t ws_size,
                              hipStream_t stream) {
    const float* xi   = (const float*)d_in[0];
    const float* Sw   = (const float*)d_in[1];
    const float* tmpl = (const float*)d_in[2];
    const float* hh   = (const float*)d_in[3];
    const float* W1   = (const float*)d_in[4];
    const float* b1   = (const float*)d_in[5];
    const float* W2   = (const float*)d_in[6];
    const float* b2   = (const float*)d_in[7];
    const float* W3   = (const float*)d_in[8];
    const float* b3   = (const float*)d_in[9];
    const float* W4   = (const float*)d_in[10];
    const float* b4   = (const float*)d_in[11];
    float* out = (float*)d_out;

    cf2* T16  = (cf2*)d_ws;                         // 16384 cf2 = 128 KB
    cf2* spec = T16 + 16384;                        // NSIG * SPEC_STRIDE cf2
    float* zarr = (float*)(spec + (size_t)NSIG * SPEC_STRIDE);

    // fwd grid: 2 half-blocks per signal + 64 twiddle-writer blocks (256 thr).
    fwd_fft_kernel<<<dim3(2*NSIG + 64), dim3(256), 0, stream>>>(xi, Sw, tmpl, T16, spec);
    xv_kernel<<<dim3(64), dim3(1024), 0, stream>>>(spec);
    inv_fft_kernel<<<dim3(BB * NTPL * 2), dim3(NTI), 0, stream>>>(spec, T16, hh, zarr);
    head_kernel<<<dim3(BB), dim3(256), 0, stream>>>(zarr, W1, b1, W2, b2, W3, b3, W4, b4, out);
}

// Round 10
// 155.232 us; speedup vs baseline: 1.0011x; 1.0011x over previous
//
#include <hip/hip_runtime.h>
#include <math.h>

#define L_LEN 16384
#define M_LEN 8192
#define KT_LEN 4096
#define BB 32
#define NTPL 50
#define SPEC_STRIDE 8224   // complex slots per signal (split layout: 4112+4096)
#define OOFF 4112          // odd-f region offset (16B aligned)
#define NSIG 166           // 64 x-signals + 2 w-signals + 100 templates
#define NTFH 512           // fwd half-block threads
#define NTI 512            // inv block (radix 2,16,16,16 ladder)
#define PI_F 3.14159265358979323846f
#define R2_F 0.70710678118654752f
// W_8192^1 = e^{-2pi i/8192}: cos(pi/4096), sin(pi/4096)
#define CW1 0.99999970586288223f
#define SW1 7.6699031874270453e-4f

typedef float cf2 __attribute__((ext_vector_type(2)));

// Lessons encoded in this structure:
//  R5: scattered per-lane twiddle loads stall VMEM -> power chain from 1 load.
//  R6: XOR swizzle + cf2 packed math + algebraic per-stage indices = best layout.
//  R7: +1-per-32 pad layout TRIPLES bank conflicts vs XOR swizzle (FFT tiles).
//  R8: __shfl_xor compiles to ds_bpermute (LDS pipe!) - shfl stage fusion loses.
//  R9: inv is not occupancy-bound (radix-8/1024t: occ 2x, dur +9%).
//  R10/R11: VOP3P pk asm for cmul + product pass: VALU 74->58%, inv 69->65us.
//  R13 REVERTED: pair-based fwd untangle broke global write coalescing (+4.7us).
//  R14 REVERTED: DPP-fused radix-2 cost +8.4us (s_nop wait-states serialize).
//  R15: radix-2-first + read-only last stage: VALU 58.6->53.5%, dur FLAT.
//  R16: X*V hoisted (50x redundancy removed, L2 -28%): dur FLAT again.
//      Three nulls => inv pinned at a barrier-latency floor at 16 waves/CU.
//  R17: fwd split into 4096-pt half-blocks: fwd REGRESSED ~11us - (a) parity-
//      interleaved stride-2 writes half-fill every 64B line from two blocks;
//      (b) 256-thr blocks halved total waves (1584 vs 2912 = 1-2 waves/SIMD).
//      BUT inv (identical code) ran 66->58us - context effect (L2 state or
//      clock), worth preserving.
//  R18 (this round): keep the half-split; fix both R17 defects:
//      (a) PARITY-SPLIT spec layout (even f at slot f/2, odd f at OOFF+f/2):
//          each half-block writes contiguous full lines. xv/inv adapted -
//          all inv phase-1 reads remain contiguous coalesced 8B streams.
//      (b) 512 thr/half-block (stages guard tid<256): 2912 waves over all
//          256 CUs, 32KB LDS -> up to 4 blocks/CU.

// Packed complex multiply: 2 VOP3P instructions.
__device__ __forceinline__ cf2 cmul(cf2 a, cf2 b) {
    cf2 t, d;
    asm("v_pk_mul_f32 %0, %1, %2 op_sel:[0,0] op_sel_hi:[0,1]"
        : "=v"(t) : "v"(a), "v"(b));
    asm("v_pk_fma_f32 %0, %1, %2, %3 op_sel:[1,1,0] op_sel_hi:[1,0,1] neg_lo:[0,1,0]"
        : "=v"(d) : "v"(a), "v"(b), "v"(t));
    return d;
}
// a * conj(b): re = ax*bx + ay*by, im = ay*bx - ax*by. 2 VOP3P insts.
__device__ __forceinline__ cf2 cmulc(cf2 a, cf2 b) {
    cf2 t, d;
    asm("v_pk_mul_f32 %0, %1, %2 op_sel:[0,0] op_sel_hi:[0,1] neg_hi:[0,1]"
        : "=v"(t) : "v"(a), "v"(b));   // {ax*bx, -ax*by}
    asm("v_pk_fma_f32 %0, %1, %2, %3 op_sel:[1,1,0] op_sel_hi:[1,0,1]"
        : "=v"(d) : "v"(a), "v"(b), "v"(t));
    return d;
}
// conj(a) * b: re = ax*bx + ay*by, im = ax*by - ay*bx. 2 VOP3P insts.
__device__ __forceinline__ cf2 cmulca(cf2 a, cf2 b) {
    cf2 t, d;
    asm("v_pk_mul_f32 %0, %1, %2 op_sel:[0,0] op_sel_hi:[0,1]"
        : "=v"(t) : "v"(a), "v"(b));   // {ax*bx, ax*by}
    asm("v_pk_fma_f32 %0, %1, %2, %3 op_sel:[1,1,0] op_sel_hi:[1,0,1] neg_hi:[1,0,0]"
        : "=v"(d) : "v"(a), "v"(b), "v"(t));
    return d;
}
// {ax+bx, ay-by}
__device__ __forceinline__ cf2 pk_addch(cf2 a, cf2 b) {
    cf2 d;
    asm("v_pk_add_f32 %0, %1, %2 neg_hi:[0,1]" : "=v"(d) : "v"(a), "v"(b));
    return d;
}
// {ax-bx, ay+by}
__device__ __forceinline__ cf2 pk_subcl(cf2 a, cf2 b) {
    cf2 d;
    asm("v_pk_add_f32 %0, %1, %2 neg_lo:[0,1]" : "=v"(d) : "v"(a), "v"(b));
    return d;
}
// {s.x - r.y, s.y + r.x}  (= s + i*r)
__device__ __forceinline__ cf2 pk_compose1(cf2 s, cf2 r) {
    cf2 d;
    asm("v_pk_add_f32 %0, %1, %2 op_sel:[0,1] op_sel_hi:[0,0] neg_lo:[0,1]"
        : "=v"(d) : "v"(s), "v"(r));
    return d;
}
// {s.x + r.y, r.x - s.y}  (= conj(s - i*r))
__device__ __forceinline__ cf2 pk_compose2(cf2 s, cf2 r) {
    cf2 d;
    asm("v_pk_add_f32 %0, %1, %2 op_sel:[0,1] op_sel_hi:[0,0] neg_hi:[1,0]"
        : "=v"(d) : "v"(s), "v"(r));
    return d;
}
template<int SIGN>
__device__ __forceinline__ cf2 rot90(cf2 z) {
    return (SIGN < 0) ? (cf2){z.y, -z.x} : (cf2){-z.y, z.x};
}
template<int SIGN>
__device__ __forceinline__ cf2 ldT(const cf2* __restrict__ T, int idx) {
    cf2 t = T[idx];
    if (SIGN > 0) t.y = -t.y;
    return t;
}

// LDS bank swizzle. Even XOR keeps float4 pair adjacency; involution.
__device__ __forceinline__ int swz(int i) { return i ^ (((i >> 5) & 15) << 1); }

// Digit reversal for a 16,16,16 DIF ladder on 4096 points (involution).
__device__ __forceinline__ int pos4(int f) {
    return ((f & 15) << 8) | (f & 0xF0) | ((f >> 8) & 15);
}

// ---------------- radix-16 pieces ----------------
template<int SIGN>
__device__ __forceinline__ void dft16(cf2 x[16]) {
    const float S = (SIGN < 0) ? -1.f : 1.f;
    const cf2 w1 = {0.9238795325112867f, S * 0.3826834323650898f};
    const cf2 w2 = {0.7071067811865476f, S * 0.7071067811865476f};
    const cf2 w3 = {0.3826834323650898f, S * 0.9238795325112867f};
    cf2 v[16];
    #pragma unroll
    for (int n1 = 0; n1 < 4; ++n1) {
        cf2 a0 = x[n1], a1 = x[n1+4], a2 = x[n1+8], a3 = x[n1+12];
        cf2 t0 = a0 + a2, t2 = a0 - a2;
        cf2 t1 = a1 + a3, t3 = rot90<SIGN>(a1 - a3);
        cf2 u0 = t0 + t1, u1 = t2 + t3;
        cf2 u2 = t0 - t1, u3 = t2 - t3;
        if (n1 == 1) { u1 = cmul(u1, w1); u2 = cmul(u2, w2); u3 = cmul(u3, w3); }
        else if (n1 == 2) { u1 = cmul(u1, w2); u2 = rot90<SIGN>(u2);
                            u3 = rot90<SIGN>(cmul(u3, w2)); }
        else if (n1 == 3) { u1 = cmul(u1, w3); u2 = rot90<SIGN>(cmul(u2, w2));
                            u3 = -cmul(u3, w1); }
        v[0*4+n1] = u0; v[1*4+n1] = u1; v[2*4+n1] = u2; v[3*4+n1] = u3;
    }
    #pragma unroll
    for (int r = 0; r < 4; ++r) {
        cf2 a0 = v[r*4+0], a1 = v[r*4+1], a2 = v[r*4+2], a3 = v[r*4+3];
        cf2 t0 = a0 + a2, t2 = a0 - a2;
        cf2 t1 = a1 + a3, t3 = rot90<SIGN>(a1 - a3);
        x[r]    = t0 + t1; x[r+4]  = t2 + t3;
        x[r+8]  = t0 - t1; x[r+12] = t2 - t3;
    }
}

template<int SIGN>
__device__ __forceinline__ void butterfly16(cf2* A, const int idx[16], cf2 w1) {
    cf2 x[16];
    #pragma unroll
    for (int n = 0; n < 16; ++n) x[n] = A[idx[n]];
    dft16<SIGN>(x);
    A[idx[0]] = x[0];
    A[idx[1]] = cmul(x[1], w1);
    const cf2 w2 = cmul(w1, w1);
    A[idx[2]] = cmul(x[2], w2);
    const cf2 w3 = cmul(w1, w2);
    A[idx[3]] = cmul(x[3], w3);
    const cf2 w4 = cmul(w2, w2);
    A[idx[4]] = cmul(x[4], w4);
    A[idx[5]] = cmul(x[5], cmul(w1, w4));
    A[idx[6]] = cmul(x[6], cmul(w2, w4));
    A[idx[7]] = cmul(x[7], cmul(w3, w4));
    const cf2 w8 = cmul(w4, w4);
    A[idx[8]]  = cmul(x[8],  w8);
    A[idx[9]]  = cmul(x[9],  cmul(w1, w8));
    A[idx[10]] = cmul(x[10], cmul(w2, w8));
    A[idx[11]] = cmul(x[11], cmul(w3, w8));
    const cf2 w12 = cmul(w4, w8);
    A[idx[12]] = cmul(x[12], w12);
    A[idx[13]] = cmul(x[13], cmul(w1, w12));
    A[idx[14]] = cmul(x[14], cmul(w2, w12));
    A[idx[15]] = cmul(x[15], cmul(w3, w12));
}

// ---------------------------------------------------------------------------
// Kernel 1 (R18): forward real FFT via TWO independent 4096-pt half-blocks,
// 512 threads each. hb < 2*NSIG -> sig = hb>>1, half = hb&1.
//   half 0: Z[2m]   = FFT4096{ c[k] + c[k+4096] }[m]
//   half 1: Z[2m+1] = FFT4096{ (c[k] - c[k+4096]) * W_8192^k }[m]
// Load + untangle run on all 512 threads; the 3 radix-16 stages (256
// butterflies) run on tid<256. Untangle writes X[2m+half] CONTIGUOUSLY to
// the parity-split spec region (coalesced full lines). Blocks
// [2*NSIG, 2*NSIG+32) write the twiddle table. W blocks (sig 64/65) fold in
// V(f) = conj(W(f)) * e^{-i pi k/8192}, k = 4094*f mod 16384.
// ---------------------------------------------------------------------------
__global__ __launch_bounds__(NTFH, 4)
void fwd_fft_kernel(const float* __restrict__ xi, const float* __restrict__ w,
                    const float* __restrict__ tmpl, cf2* __restrict__ Tw,
                    cf2* __restrict__ spec) {
    __shared__ __attribute__((aligned(16))) cf2 A[4096];   // 32 KB
    const int hb = blockIdx.x;
    const int tid = threadIdx.x;

    if (hb >= 2*NSIG) {   // twiddle writer: T[k] = e^{-2 pi i k / 16384}
        const int k = (hb - 2*NSIG) * NTFH + tid;
        const int quad = k >> 12, mm = k & 4095;
        float s, c; __sincosf(PI_F * (float)mm / 8192.f, &s, &c);
        cf2 v;   // (cos th, -sin th), th = pi k/8192 = quad*pi/2 + t
        if      (quad == 0) v = (cf2){ c, -s};
        else if (quad == 1) v = (cf2){-s, -c};
        else if (quad == 2) v = (cf2){-c,  s};
        else                v = (cf2){ s,  c};
        Tw[k] = v;
        return;
    }

    const int sig = hb >> 1, half = hb & 1;
    const float* src;
    int nre;
    if (sig < 64)      { src = xi   + sig * L_LEN;         nre = L_LEN; }
    else if (sig < 66) { src = w    + (sig - 64) * L_LEN;  nre = L_LEN; }
    else               { src = tmpl + (sig - 66) * KT_LEN; nre = KT_LEN; }
    const bool isW = (sig >= 64 && sig < 66);
    const int nf4 = nre >> 2;                 // float4 count of source
    const float4* s4 = (const float4*)src;

    // Load + fused radix-2 (DIF). j = complex-pair float4 index in [0,2048).
    const cf2 w1c = (cf2){CW1, -SW1};         // W_8192^1
    #pragma unroll
    for (int mm = 0; mm < 4; ++mm) {
        const int j = tid + 512*mm;
        float4 a = (j < nf4)        ? s4[j]        : make_float4(0.f,0.f,0.f,0.f);
        float4 b = (j + 2048 < nf4) ? s4[j + 2048] : make_float4(0.f,0.f,0.f,0.f);
        cf2 c0 = (cf2){a.x, a.y}, c1 = (cf2){a.z, a.w};
        cf2 d0 = (cf2){b.x, b.y}, d1 = (cf2){b.z, b.w};
        cf2 h0, h1;
        if (half == 0) { h0 = c0 + d0; h1 = c1 + d1; }
        else {
            float sn, cs; __sincosf(-PI_F * (float)j / 2048.f, &sn, &cs);
            cf2 wk = (cf2){cs, sn};           // W_8192^{2j}
            h0 = cmul(c0 - d0, wk);
            h1 = cmul(c1 - d1, cmul(wk, w1c));
        }
        const int g = j ^ ((j >> 4) & 15);    // float4 LDS index (swz(2j)/2)
        ((float4*)A)[g] = make_float4(h0.x, h0.y, h1.x, h1.y);
    }
    __syncthreads();

    if (tid < 256) {   // stage 1: stride 256, w1 = W_4096^tid
        const int jx = tid ^ (((tid >> 5) & 7) << 1);
        int idx[16];
        #pragma unroll
        for (int n = 0; n < 16; ++n) idx[n] = (jx ^ ((n & 1) << 4)) + 256*n;
        float sn, cs; __sincosf(-PI_F * (float)tid / 2048.f, &sn, &cs);
        butterfly16<-1>(A, idx, (cf2){cs, sn});
    }
    __syncthreads();
    if (tid < 256) {   // stage 2: stride 16, w1 = W_256^j
        const int q = tid >> 4, j = tid & 15;
        const int base = q << 8, qb = q & 1;
        int idx[16];
        #pragma unroll
        for (int n = 0; n < 16; ++n)
            idx[n] = base + 16*(n ^ qb) + (j ^ (((n >> 1) & 7) << 1));
        float sn, cs; __sincosf(-PI_F * (float)j / 128.f, &sn, &cs);
        butterfly16<-1>(A, idx, (cf2){cs, sn});
    }
    __syncthreads();
    if (tid < 256) {   // stage 3: stride 1, twiddle-free dft16, b128 in/out.
        const int bb = 16 * (tid ^ ((tid >> 4) & 1));
        const int m3 = ((tid >> 1) & 7) << 1;
        cf2 x[16];
        #pragma unroll
        for (int e = 0; e < 8; ++e) {
            float4 v = ((const float4*)A)[(bb + ((2*e) ^ m3)) >> 1];
            x[2*e]     = (cf2){v.x, v.y};
            x[2*e + 1] = (cf2){v.z, v.w};
        }
        dft16<-1>(x);
        #pragma unroll
        for (int e = 0; e < 8; ++e)
            ((float4*)A)[(bb + ((2*e) ^ m3)) >> 1] =
                make_float4(x[2*e].x, x[2*e].y, x[2*e+1].x, x[2*e+1].y);
    }
    __syncthreads();

    // Untangle this half's parity: f = 2m+half, partner 8192-f (same parity).
    // Writes CONTIGUOUS slots m of the parity region (coalesced full lines).
    cf2* outh = spec + (size_t)sig * SPEC_STRIDE + (half ? OOFF : 0);
    #pragma unroll
    for (int mm = 0; mm < 8; ++mm) {
        const int m = tid + 512*mm;
        const int mb = half ? (4095 - m) : ((4096 - m) & 4095);
        const int f = 2*m + half;
        cf2 Za = A[swz(pos4(m))];
        cf2 Zb = A[swz(pos4(mb))];
        cf2 E = (cf2){0.5f*(Za.x + Zb.x), 0.5f*(Za.y - Zb.y)};
        cf2 D = (cf2){Za.x - Zb.x, Za.y + Zb.y};
        cf2 O = (cf2){0.5f*D.y, -0.5f*D.x};
        float sn, cs;
        __sincosf(-PI_F * (float)f / 8192.f, &sn, &cs);
        cf2 val = E + (cf2){cs*O.x - sn*O.y, cs*O.y + sn*O.x};
        if (isW) {   // V(f) = conj(W(f)) * e^{-i pi k/8192}, k exact int mod
            const int k = (4094 * f) & (L_LEN - 1);
            float psn, pcs; __sincosf(-PI_F * (float)k / 8192.f, &psn, &pcs);
            val = cmul((cf2){val.x, -val.y}, (cf2){pcs, psn});
        }
        outh[m] = val;
    }
    if (half == 0 && tid == 0) {   // f = 8192 -> even slot 4096
        cf2 Za = A[0];
        cf2 val = (cf2){Za.x - Za.y, 0.f};
        if (isW) val = (cf2){-val.x, 0.f};
        outh[4096] = val;
    }
}

// ---------------------------------------------------------------------------
// Kernel 1b (R16/R18): XV = X*V, in-place, parity-split layout.
// Even region: float4 [0,2048) + scalar slot 4096; odd: float4 [2056,4104).
// ---------------------------------------------------------------------------
__global__ __launch_bounds__(1024)
void xv_kernel(cf2* __restrict__ spec) {
    const int bc = blockIdx.x;          // 0..63 = b*2 + c
    cf2* Xs = spec + (size_t)bc * SPEC_STRIDE;
    const cf2* Vs = spec + (size_t)(64 + (bc & 1)) * SPEC_STRIDE;
    const int tid = threadIdx.x;
    float4* X4 = (float4*)Xs;
    const float4* V4 = (const float4*)Vs;
    #pragma unroll
    for (int m = 0; m < 2; ++m) {
        const int p = tid + 1024*m;     // even region float4 [0,2048)
        float4 xv = X4[p], vv = V4[p];
        cf2 a = cmul((cf2){xv.x, xv.y}, (cf2){vv.x, vv.y});
        cf2 b = cmul((cf2){xv.z, xv.w}, (cf2){vv.z, vv.w});
        X4[p] = make_float4(a.x, a.y, b.x, b.y);
    }
    #pragma unroll
    for (int m = 0; m < 2; ++m) {
        const int p = 2056 + tid + 1024*m;   // odd region float4
        float4 xv = X4[p], vv = V4[p];
        cf2 a = cmul((cf2){xv.x, xv.y}, (cf2){vv.x, vv.y});
        cf2 b = cmul((cf2){xv.z, xv.w}, (cf2){vv.z, vv.w});
        X4[p] = make_float4(a.x, a.y, b.x, b.y);
    }
    if (tid == 0) Xs[4096] = cmul(Xs[4096], Vs[4096]);   // f = 8192
}

// ---------------------------------------------------------------------------
// Kernel 2 (R15+R16+R18): product (XV * conj(H), parity-split reads) +
// Hermitian pack + FIRST radix-2 stage fused in registers. Then 16,16,16
// stages on the two 4096-halves; stride-1 last stage is read-only + max.
// Z' carries 2x (0.5 dropped) -> divide by 2*M*hh.
// Slot map: f even -> Xe[f>>1]; f odd -> Xo[f>>1].
// ---------------------------------------------------------------------------
__global__ __launch_bounds__(NTI, 4)
void inv_fft_kernel(const cf2* __restrict__ spec, const cf2* __restrict__ T,
                    const float* __restrict__ hh, float* __restrict__ zarr) {
    __shared__ __attribute__((aligned(16))) cf2 A[M_LEN];   // 64 KB
    const int idx0 = blockIdx.x;
    const int c = idx0 & 1;
    const int n = (idx0 >> 1) % NTPL;
    const int b = idx0 / (2 * NTPL);
    const int tid = threadIdx.x;

    const cf2* Xe = spec + (size_t)(b*2 + c)      * SPEC_STRIDE;   // = XV even
    const cf2* He = spec + (size_t)(66 + n*2 + c) * SPEC_STRIDE;
    const cf2* Xo = Xe + OOFF;
    const cf2* Ho = He + OOFF;
    const float4* T4 = (const float4*)T;

    #pragma unroll
    for (int m = 0; m < 2; ++m) {
        const int tp = tid + 512*m;
        // f0 = 2tp (even), f1 = 2tp+1 (odd)
        cf2 PA0 = cmulc(Xe[tp],        He[tp]);          // X[f0]
        cf2 PA1 = cmulc(Xo[tp],        Ho[tp]);          // X[f1]
        cf2 QB0 = cmulc(Xe[2048 + tp], He[2048 + tp]);   // X[4096+f0]
        cf2 QB1 = cmulc(Xo[2048 + tp], Ho[2048 + tp]);   // X[4096+f1]
        cf2 PB0 = cmulc(Xe[2048 - tp], He[2048 - tp]);   // X[4096-f0]
        cf2 PB1 = cmulc(Xo[2047 - tp], Ho[2047 - tp]);   // X[4096-f1]
        cf2 QA0 = cmulc(Xe[4096 - tp], He[4096 - tp]);   // X[8192-f0]
        cf2 QA1 = cmulc(Xo[4095 - tp], Ho[4095 - tp]);   // X[8192-f1]
        const int f0 = 2*tp;
        float4 tf4 = T4[tp];            // T[f0], T[f1]
        float4 t2a = T4[2*tp];          // T[2f0] in .xy
        float4 t2b = T4[2*tp + 1];      // T[2f1] in .xy
        cf2 Tf0 = (cf2){tf4.x, tf4.y}, Tf1 = (cf2){tf4.z, tf4.w};
        cf2 T20 = (cf2){t2a.x, t2a.y}, T21 = (cf2){t2b.x, t2b.y};
        // --- f0 ---
        cf2 SpA0 = pk_addch(PA0, QA0), SmA0 = pk_subcl(PA0, QA0);
        cf2 RA0 = cmulca(Tf0, SmA0);
        cf2 ZA1_0 = pk_compose1(SpA0, RA0);     // Z'[f0]
        cf2 ZA2_0 = pk_compose2(SpA0, RA0);     // Z'[8192-f0]
        cf2 tB0 = (cf2){-Tf0.y, -Tf0.x};        // T[4096-f0]
        cf2 SpB0 = pk_addch(PB0, QB0), SmB0 = pk_subcl(PB0, QB0);
        cf2 RB0 = cmulca(tB0, SmB0);
        cf2 ZB1_0 = pk_compose1(SpB0, RB0);     // Z'[4096-f0]
        cf2 ZB2_0 = pk_compose2(SpB0, RB0);     // Z'[4096+f0]
        cf2 top0 = ZA1_0 + ZB2_0;
        cf2 bot0 = cmulca(T20, ZA1_0 - ZB2_0);
        // --- f1 ---
        cf2 SpA1 = pk_addch(PA1, QA1), SmA1 = pk_subcl(PA1, QA1);
        cf2 RA1 = cmulca(Tf1, SmA1);
        cf2 ZA1_1 = pk_compose1(SpA1, RA1);
        cf2 ZA2_1 = pk_compose2(SpA1, RA1);
        cf2 tB1 = (cf2){-Tf1.y, -Tf1.x};
        cf2 SpB1 = pk_addch(PB1, QB1), SmB1 = pk_subcl(PB1, QB1);
        cf2 RB1 = cmulca(tB1, SmB1);
        cf2 ZB1_1 = pk_compose1(SpB1, RB1);
        cf2 ZB2_1 = pk_compose2(SpB1, RB1);
        cf2 top1 = ZA1_1 + ZB2_1;
        cf2 bot1 = cmulca(T21, ZA1_1 - ZB2_1);
        // coalesced swizzled float4 writes for the fwd side
        const int gt = tp ^ ((tp >> 4) & 15);
        ((float4*)A)[gt]        = make_float4(top0.x, top0.y, top1.x, top1.y);
        ((float4*)A)[2048 + gt] = make_float4(bot0.x, bot0.y, bot1.x, bot1.y);
        // rev-side butterflies (skip f0 == 0: its pair (4096,8192) is invalid;
        // the fwd butterfly above already used the correct self-paired Z'[4096])
        if (tp > 0) {
            cf2 tr0 = ZB1_0 + ZA2_0;
            cf2 dr0 = cmul(ZB1_0 - ZA2_0, T20);
            A[swz(4096 - f0)] = tr0;
            A[swz(8192 - f0)] = -dr0;
        }
        cf2 tr1 = ZB1_1 + ZA2_1;
        cf2 dr1 = cmul(ZB1_1 - ZA2_1, T21);
        A[swz(4096 - f0 - 1)] = tr1;
        A[swz(8192 - f0 - 1)] = -dr1;
    }
    if (tid == 0) {   // f = 2048 butterfly (2048, 6144), Wi^2048 = +i
        cf2 P = cmulc(Xe[1024], He[1024]);   // X[2048]
        cf2 Q = cmulc(Xe[3072], He[3072]);   // X[6144]
        cf2 Tc = (cf2){R2_F, -R2_F};         // T[2048]
        cf2 Sp = pk_addch(P, Q), Sm = pk_subcl(P, Q);
        cf2 R = cmulca(Tc, Sm);
        cf2 Z1 = pk_compose1(Sp, R), Z2 = pk_compose2(Sp, R);
        cf2 d = Z1 - Z2;
        A[swz(2048)] = Z1 + Z2;
        A[swz(6144)] = (cf2){-d.y, d.x};
    }
    __syncthreads();

    {   // stage 1 of the 4096-halves: stride 256, w1 = conj(T[4j])
        const int h = tid >> 8, j = tid & 255;
        const int Hb = h << 12;
        const int jx = j ^ (((j >> 5) & 7) << 1);
        int idx[16];
        #pragma unroll
        for (int nn = 0; nn < 16; ++nn)
            idx[nn] = Hb + 256*nn + (jx ^ ((nn & 1) << 4));
        butterfly16<+1>(A, idx, ldT<+1>(T, 4*j));
    }
    __syncthreads();
    {   // stage 2: stride 16, w1 = conj(T[64j])
        const int h = tid >> 8, q = (tid >> 4) & 15, j = tid & 15;
        const int base = (h << 12) + (q << 8);
        const int qb = q & 1;
        int idx[16];
        #pragma unroll
        for (int nn = 0; nn < 16; ++nn)
            idx[nn] = base + 16*(nn ^ qb) + (j ^ (((nn >> 1) & 7) << 1));
        butterfly16<+1>(A, idx, ldT<+1>(T, 64*j));
    }
    __syncthreads();

    // stage 3: stride 1, twiddle = W_16^0 = 1 -> read-only dft16 + max.
    float mx = -INFINITY;
    {
        const int bb = 16 * (tid ^ ((tid >> 4) & 1));
        const int m3 = ((tid >> 1) & 7) << 1;
        cf2 x[16];
        #pragma unroll
        for (int e = 0; e < 8; ++e) {
            float4 v = ((const float4*)A)[(bb + ((2*e) ^ m3)) >> 1];
            x[2*e]     = (cf2){v.x, v.y};
            x[2*e + 1] = (cf2){v.z, v.w};
        }
        dft16<+1>(x);
        #pragma unroll
        for (int nn = 0; nn < 16; ++nn)
            mx = fmaxf(mx, fmaxf(x[nn].x, x[nn].y));
    }
    __syncthreads();   // all stage-3 reads done before reusing A as scratch
    for (int off = 32; off > 0; off >>= 1)
        mx = fmaxf(mx, __shfl_xor(mx, off));
    const int lane = tid & 63, wv = tid >> 6;   // 8 waves
    float* redf = (float*)A;
    if (lane == 0) redf[wv] = mx;
    __syncthreads();
    if (tid == 0) {
        float mm = redf[0];
        for (int i = 1; i < NTI/64; ++i) mm = fmaxf(mm, redf[i]);
        zarr[(b*2 + c)*NTPL + n] = mm / (2.f * (float)M_LEN * hh[n*2 + c]);
    }
}

// ---------------------------------------------------------------------------
// Kernel 3: tiny CNN/MLP head. One block per batch element.
// R12: all weights staged in LDS (coalesced), all MAC loops unrolled over
// LDS reads, fc1 parallelized 32 outputs x 8 lanes + shfl_xor tree.
// ---------------------------------------------------------------------------
#define W1_OFF 0        // 16x6 = 96
#define B1_OFF 96       // 16
#define W2_OFF 112      // 32x48 = 1536
#define B2_OFF 1648     // 32
#define W3_OFF 1680     // 32x132 (padded from 128) = 4224
#define B3_OFF 5904     // 32
#define W4_OFF 5936     // 2x32 = 64
#define B4_OFF 6000     // 2
#define WSM_SZ 6002

__global__ __launch_bounds__(256)
void head_kernel(const float* __restrict__ zarr,
                 const float* __restrict__ W1, const float* __restrict__ b1,
                 const float* __restrict__ W2, const float* __restrict__ b2,
                 const float* __restrict__ W3, const float* __restrict__ b3,
                 const float* __restrict__ W4, const float* __restrict__ b4,
                 float* __restrict__ out) {
    __shared__ float wsm[WSM_SZ];
    __shared__ float zl[2*NTPL];
    __shared__ float s1[16*48];
    __shared__ float p1[16*16];
    __shared__ float s2[32*14];
    __shared__ float hflat[128];
    __shared__ float h1[32];
    const int b = blockIdx.x, tid = threadIdx.x;

    for (int i = tid; i < 96;   i += 256) wsm[W1_OFF + i] = W1[i];
    if (tid < 16)                         wsm[B1_OFF + tid] = b1[tid];
    for (int i = tid; i < 1536; i += 256) wsm[W2_OFF + i] = W2[i];
    if (tid < 32)                         wsm[B2_OFF + tid] = b2[tid];
    for (int i = tid; i < 4096; i += 256)
        wsm[W3_OFF + (i >> 7)*132 + (i & 127)] = W3[i];
    if (tid < 32)                         wsm[B3_OFF + tid] = b3[tid];
    if (tid < 64)                         wsm[W4_OFF + tid] = W4[tid];
    if (tid < 2)                          wsm[B4_OFF + tid] = b4[tid];
    for (int i = tid; i < 2*NTPL; i += 256) zl[i] = zarr[b*2*NTPL + i];
    __syncthreads();

    for (int i = tid; i < 16*48; i += 256) {
        const int o = i / 48, t = i % 48;
        float acc = wsm[B1_OFF + o];
        #pragma unroll
        for (int cc = 0; cc < 2; ++cc)
            #pragma unroll
            for (int k = 0; k < 3; ++k)
                acc += zl[cc*NTPL + t + k] * wsm[W1_OFF + o*6 + cc*3 + k];
        s1[i] = 1.f / (1.f + __expf(-acc));
    }
    __syncthreads();
    for (int i = tid; i < 16*16; i += 256) {
        const int o = i / 16, u = i % 16;
        p1[i] = fmaxf(fmaxf(s1[o*48 + 3*u], s1[o*48 + 3*u+1]), s1[o*48 + 3*u+2]);
    }
    __syncthreads();
    for (int i = tid; i < 32*14; i += 256) {
        const int o = i / 14, t = i % 14;
        float acc = wsm[B2_OFF + o];
        #pragma unroll
        for (int cc = 0; cc < 16; ++cc)
            #pragma unroll
            for (int k = 0; k < 3; ++k)
                acc += p1[cc*16 + t + k] * wsm[W2_OFF + o*48 + cc*3 + k];
        s2[o*14 + t] = 1.f / (1.f + __expf(-acc));
    }
    __syncthreads();
    for (int i = tid; i < 128; i += 256) {
        const int o = i / 4, u = i % 4;
        hflat[i] = fmaxf(fmaxf(s2[o*14 + 3*u], s2[o*14 + 3*u+1]), s2[o*14 + 3*u+2]);
    }
    __syncthreads();
    {
        const int o = tid >> 3, lg = tid & 7;
        float acc = 0.f;
        #pragma unroll
        for (int k = 0; k < 16; ++k)
            acc += hflat[lg + 8*k] * wsm[W3_OFF + o*132 + lg + 8*k];
        acc += __shfl_xor(acc, 1);
        acc += __shfl_xor(acc, 2);
        acc += __shfl_xor(acc, 4);
        if (lg == 0) h1[o] = fmaxf(acc + wsm[B3_OFF + o], 0.f);
    }
    __syncthreads();
    if (tid < 64) {
        const int o = tid >> 5, j = tid & 31;
        float p = h1[j] * wsm[W4_OFF + o*32 + j];
        p += __shfl_xor(p, 1);
        p += __shfl_xor(p, 2);
        p += __shfl_xor(p, 4);
        p += __shfl_xor(p, 8);
        p += __shfl_xor(p, 16);
        if (j == 0) out[b*2 + o] = p + wsm[B4_OFF + o];
    }
}

extern "C" void kernel_launch(void* const* d_in, const int* in_sizes, int n_in,
                              void* d_out, int out_size, void* d_ws, size_t ws_size,
                              hipStream_t stream) {
    const float* xi   = (const float*)d_in[0];
    const float* Sw   = (const float*)d_in[1];
    const float* tmpl = (const float*)d_in[2];
    const float* hh   = (const float*)d_in[3];
    const float* W1   = (const float*)d_in[4];
    const float* b1   = (const float*)d_in[5];
    const float* W2   = (const float*)d_in[6];
    const float* b2   = (const float*)d_in[7];
    const float* W3   = (const float*)d_in[8];
    const float* b3   = (const float*)d_in[9];
    const float* W4   = (const float*)d_in[10];
    const float* b4   = (const float*)d_in[11];
    float* out = (float*)d_out;

    cf2* T16  = (cf2*)d_ws;                         // 16384 cf2 = 128 KB
    cf2* spec = T16 + 16384;                        // NSIG * SPEC_STRIDE cf2
    float* zarr = (float*)(spec + (size_t)NSIG * SPEC_STRIDE);

    // fwd grid: 2 half-blocks per signal + 32 twiddle-writer blocks (512 thr).
    fwd_fft_kernel<<<dim3(2*NSIG + 32), dim3(NTFH), 0, stream>>>(xi, Sw, tmpl, T16, spec);
    xv_kernel<<<dim3(64), dim3(1024), 0, stream>>>(spec);
    inv_fft_kernel<<<dim3(BB * NTPL * 2), dim3(NTI), 0, stream>>>(spec, T16, hh, zarr);
    head_kernel<<<dim3(BB), dim3(256), 0, stream>>>(zarr, W1, b1, W2, b2, W3, b3, W4, b4, out);
}

// Round 11
// 152.209 us; speedup vs baseline: 1.0210x; 1.0199x over previous
//
#include <hip/hip_runtime.h>
#include <math.h>

#define L_LEN 16384
#define M_LEN 8192
#define KT_LEN 4096
#define BB 32
#define NTPL 50
#define SPEC_STRIDE 8224   // complex slots per signal (split layout: 4112+4096)
#define OOFF 4112          // odd-f region offset (16B aligned)
#define NSIG 166           // 64 x-signals + 2 w-signals + 100 templates
#define NTF 1024           // fwd block (monolithic radix-8 ladder)
#define NTI 512            // inv block (radix 2,16,16,16 ladder)
#define PI_F 3.14159265358979323846f
#define R2_F 0.70710678118654752f
// cos/sin(2*pi/16): fwd stage-4 twiddle base (radix-8 ladder)
#define C8 0.92387953251128674f
#define S8 0.38268343236508978f

typedef float cf2 __attribute__((ext_vector_type(2)));

// Lessons encoded in this structure:
//  R5: scattered per-lane twiddle loads stall VMEM -> power chain from 1 load.
//  R6: XOR swizzle + cf2 packed math + algebraic per-stage indices = best layout.
//  R7: +1-per-32 pad layout TRIPLES bank conflicts vs XOR swizzle (FFT tiles).
//  R8: __shfl_xor compiles to ds_bpermute (LDS pipe!) - shfl stage fusion loses.
//  R9: inv is not occupancy-bound (radix-8/1024t: occ 2x, dur +9%).
//  R10/R11: VOP3P pk asm for cmul + product pass: VALU 74->58%, inv 69->65us.
//  R13 REVERTED: pair-based fwd untangle broke global write coalescing (+4.7us).
//  R14 REVERTED: DPP-fused radix-2 cost +8.4us (s_nop wait-states serialize).
//  R15: radix-2-first + read-only last stage: VALU 58.6->53.5%, dur FLAT.
//  R16: X*V hoisted (50x redundancy removed, L2 -28%): dur FLAT again.
//  R17/R18: fwd half-split REGRESSED fwd ~9us (per-block fixed cost doesn't
//      amortize) but revealed a LAYOUT effect: inv with parity-split spec
//      (even f at slot f/2, odd at OOFF+f/2; product reads = pure contiguous
//      streams) runs 60.5us vs 66us linear. fwd-monolithic and parity-split
//      are independent wins.
//  R19 (this round): recombine - fwd = R8 monolithic radix-8 (fastest fwd),
//      writing parity-split output (even lanes -> even region, odd lanes ->
//      odd region; two coalesced 256B streams per wave). xv/inv byte-identical
//      to R18's (inv's 60.5us configuration).

// Packed complex multiply: 2 VOP3P instructions.
__device__ __forceinline__ cf2 cmul(cf2 a, cf2 b) {
    cf2 t, d;
    asm("v_pk_mul_f32 %0, %1, %2 op_sel:[0,0] op_sel_hi:[0,1]"
        : "=v"(t) : "v"(a), "v"(b));
    asm("v_pk_fma_f32 %0, %1, %2, %3 op_sel:[1,1,0] op_sel_hi:[1,0,1] neg_lo:[0,1,0]"
        : "=v"(d) : "v"(a), "v"(b), "v"(t));
    return d;
}
// a * conj(b): re = ax*bx + ay*by, im = ay*bx - ax*by. 2 VOP3P insts.
__device__ __forceinline__ cf2 cmulc(cf2 a, cf2 b) {
    cf2 t, d;
    asm("v_pk_mul_f32 %0, %1, %2 op_sel:[0,0] op_sel_hi:[0,1] neg_hi:[0,1]"
        : "=v"(t) : "v"(a), "v"(b));   // {ax*bx, -ax*by}
    asm("v_pk_fma_f32 %0, %1, %2, %3 op_sel:[1,1,0] op_sel_hi:[1,0,1]"
        : "=v"(d) : "v"(a), "v"(b), "v"(t));
    return d;
}
// conj(a) * b: re = ax*bx + ay*by, im = ax*by - ay*bx. 2 VOP3P insts.
__device__ __forceinline__ cf2 cmulca(cf2 a, cf2 b) {
    cf2 t, d;
    asm("v_pk_mul_f32 %0, %1, %2 op_sel:[0,0] op_sel_hi:[0,1]"
        : "=v"(t) : "v"(a), "v"(b));   // {ax*bx, ax*by}
    asm("v_pk_fma_f32 %0, %1, %2, %3 op_sel:[1,1,0] op_sel_hi:[1,0,1] neg_hi:[1,0,0]"
        : "=v"(d) : "v"(a), "v"(b), "v"(t));
    return d;
}
// {ax+bx, ay-by}
__device__ __forceinline__ cf2 pk_addch(cf2 a, cf2 b) {
    cf2 d;
    asm("v_pk_add_f32 %0, %1, %2 neg_hi:[0,1]" : "=v"(d) : "v"(a), "v"(b));
    return d;
}
// {ax-bx, ay+by}
__device__ __forceinline__ cf2 pk_subcl(cf2 a, cf2 b) {
    cf2 d;
    asm("v_pk_add_f32 %0, %1, %2 neg_lo:[0,1]" : "=v"(d) : "v"(a), "v"(b));
    return d;
}
// {s.x - r.y, s.y + r.x}  (= s + i*r)
__device__ __forceinline__ cf2 pk_compose1(cf2 s, cf2 r) {
    cf2 d;
    asm("v_pk_add_f32 %0, %1, %2 op_sel:[0,1] op_sel_hi:[0,0] neg_lo:[0,1]"
        : "=v"(d) : "v"(s), "v"(r));
    return d;
}
// {s.x + r.y, r.x - s.y}  (= conj(s - i*r))
__device__ __forceinline__ cf2 pk_compose2(cf2 s, cf2 r) {
    cf2 d;
    asm("v_pk_add_f32 %0, %1, %2 op_sel:[0,1] op_sel_hi:[0,0] neg_hi:[1,0]"
        : "=v"(d) : "v"(s), "v"(r));
    return d;
}
template<int SIGN>
__device__ __forceinline__ cf2 rot90(cf2 z) {
    return (SIGN < 0) ? (cf2){z.y, -z.x} : (cf2){-z.y, z.x};
}
template<int SIGN>
__device__ __forceinline__ cf2 ldT(const cf2* __restrict__ T, int idx) {
    cf2 t = T[idx];
    if (SIGN > 0) t.y = -t.y;
    return t;
}

// LDS bank swizzle. Even XOR keeps float4 pair adjacency; involution.
__device__ __forceinline__ int swz(int i) { return i ^ (((i >> 5) & 15) << 1); }

// Digit reversal for fwd's radix 8,8,8,8,2 DIF ladder.
__device__ __forceinline__ int pos8(int f) {
    return ((f & 7) << 10) | (((f >> 3) & 7) << 7) |
           (((f >> 6) & 7) << 4) | (((f >> 9) & 7) << 1) | ((f >> 12) & 1);
}

// ---------------- radix-16 pieces (inv kernel) ----------------
template<int SIGN>
__device__ __forceinline__ void dft16(cf2 x[16]) {
    const float S = (SIGN < 0) ? -1.f : 1.f;
    const cf2 w1 = {0.9238795325112867f, S * 0.3826834323650898f};
    const cf2 w2 = {0.7071067811865476f, S * 0.7071067811865476f};
    const cf2 w3 = {0.3826834323650898f, S * 0.9238795325112867f};
    cf2 v[16];
    #pragma unroll
    for (int n1 = 0; n1 < 4; ++n1) {
        cf2 a0 = x[n1], a1 = x[n1+4], a2 = x[n1+8], a3 = x[n1+12];
        cf2 t0 = a0 + a2, t2 = a0 - a2;
        cf2 t1 = a1 + a3, t3 = rot90<SIGN>(a1 - a3);
        cf2 u0 = t0 + t1, u1 = t2 + t3;
        cf2 u2 = t0 - t1, u3 = t2 - t3;
        if (n1 == 1) { u1 = cmul(u1, w1); u2 = cmul(u2, w2); u3 = cmul(u3, w3); }
        else if (n1 == 2) { u1 = cmul(u1, w2); u2 = rot90<SIGN>(u2);
                            u3 = rot90<SIGN>(cmul(u3, w2)); }
        else if (n1 == 3) { u1 = cmul(u1, w3); u2 = rot90<SIGN>(cmul(u2, w2));
                            u3 = -cmul(u3, w1); }
        v[0*4+n1] = u0; v[1*4+n1] = u1; v[2*4+n1] = u2; v[3*4+n1] = u3;
    }
    #pragma unroll
    for (int r = 0; r < 4; ++r) {
        cf2 a0 = v[r*4+0], a1 = v[r*4+1], a2 = v[r*4+2], a3 = v[r*4+3];
        cf2 t0 = a0 + a2, t2 = a0 - a2;
        cf2 t1 = a1 + a3, t3 = rot90<SIGN>(a1 - a3);
        x[r]    = t0 + t1; x[r+4]  = t2 + t3;
        x[r+8]  = t0 - t1; x[r+12] = t2 - t3;
    }
}

template<int SIGN>
__device__ __forceinline__ void butterfly16(cf2* A, const int idx[16], cf2 w1) {
    cf2 x[16];
    #pragma unroll
    for (int n = 0; n < 16; ++n) x[n] = A[idx[n]];
    dft16<SIGN>(x);
    A[idx[0]] = x[0];
    A[idx[1]] = cmul(x[1], w1);
    const cf2 w2 = cmul(w1, w1);
    A[idx[2]] = cmul(x[2], w2);
    const cf2 w3 = cmul(w1, w2);
    A[idx[3]] = cmul(x[3], w3);
    const cf2 w4 = cmul(w2, w2);
    A[idx[4]] = cmul(x[4], w4);
    A[idx[5]] = cmul(x[5], cmul(w1, w4));
    A[idx[6]] = cmul(x[6], cmul(w2, w4));
    A[idx[7]] = cmul(x[7], cmul(w3, w4));
    const cf2 w8 = cmul(w4, w4);
    A[idx[8]]  = cmul(x[8],  w8);
    A[idx[9]]  = cmul(x[9],  cmul(w1, w8));
    A[idx[10]] = cmul(x[10], cmul(w2, w8));
    A[idx[11]] = cmul(x[11], cmul(w3, w8));
    const cf2 w12 = cmul(w4, w8);
    A[idx[12]] = cmul(x[12], w12);
    A[idx[13]] = cmul(x[13], cmul(w1, w12));
    A[idx[14]] = cmul(x[14], cmul(w2, w12));
    A[idx[15]] = cmul(x[15], cmul(w3, w12));
}

// ---------------- radix-8 pieces (fwd kernel) ----------------
template<int SIGN>
__device__ __forceinline__ void dft8(cf2 x[8]) {
    const cf2 w81 = { R2_F, SIGN * R2_F };
    const cf2 w83 = { -R2_F, SIGN * R2_F };
    cf2 u0 = x[0] + x[4], u1 = x[1] + x[5], u2 = x[2] + x[6], u3 = x[3] + x[7];
    cf2 v0 = x[0] - x[4];
    cf2 v1 = cmul(x[1] - x[5], w81);
    cf2 v2 = rot90<SIGN>(x[2] - x[6]);
    cf2 v3 = cmul(x[3] - x[7], w83);
    cf2 t0 = u0 + u2, t2 = u0 - u2;
    cf2 t1 = u1 + u3, t3 = rot90<SIGN>(u1 - u3);
    x[0] = t0 + t1; x[2] = t2 + t3; x[4] = t0 - t1; x[6] = t2 - t3;
    cf2 s0 = v0 + v2, s2 = v0 - v2;
    cf2 s1 = v1 + v3, s3 = rot90<SIGN>(v1 - v3);
    x[1] = s0 + s1; x[3] = s2 + s3; x[5] = s0 - s1; x[7] = s2 - s3;
}

template<int SIGN>
__device__ __forceinline__ void butterfly8(cf2* A, const int idx[8], cf2 w1) {
    cf2 x[8];
    #pragma unroll
    for (int n = 0; n < 8; ++n) x[n] = A[idx[n]];
    dft8<SIGN>(x);
    A[idx[0]] = x[0];
    A[idx[1]] = cmul(x[1], w1);
    const cf2 w2 = cmul(w1, w1);
    A[idx[2]] = cmul(x[2], w2);
    const cf2 w3 = cmul(w1, w2);
    A[idx[3]] = cmul(x[3], w3);
    const cf2 w4 = cmul(w2, w2);
    A[idx[4]] = cmul(x[4], w4);
    A[idx[5]] = cmul(x[5], cmul(w1, w4));
    A[idx[6]] = cmul(x[6], cmul(w2, w4));
    A[idx[7]] = cmul(x[7], cmul(w3, w4));
}

// ---------------------------------------------------------------------------
// Kernel 1 (R19): forward real FFT, monolithic radix 8,8,8,8,2 ladder (R8's
// fastest-fwd structure), 1024 threads. Untangle writes the PARITY-SPLIT
// layout: even f -> slot f/2, odd f -> OOFF + f/2. Per wave, even lanes emit
// 32 consecutive even slots and odd lanes 32 consecutive odd slots (two
// coalesced 256B streams). Blocks [NSIG, NSIG+16) write the twiddle table.
// W blocks (sig 64/65) fold in V(f) = conj(W(f)) * e^{-i pi k/8192}.
// ---------------------------------------------------------------------------
__global__ __launch_bounds__(NTF, 4)
void fwd_fft_kernel(const float* __restrict__ xi, const float* __restrict__ w,
                    const float* __restrict__ tmpl, cf2* __restrict__ Tw,
                    cf2* __restrict__ spec) {
    __shared__ __attribute__((aligned(16))) cf2 A[M_LEN];   // 64 KB
    const int sig = blockIdx.x;
    const int tid = threadIdx.x;

    if (sig >= NSIG) {   // twiddle writer: T[k] = e^{-2 pi i k / 16384}
        const int k = (sig - NSIG) * NTF + tid;
        const int quad = k >> 12, mm = k & 4095;
        float s, c; __sincosf(PI_F * (float)mm / 8192.f, &s, &c);
        cf2 v;   // (cos th, -sin th), th = pi k/8192 = quad*pi/2 + t
        if      (quad == 0) v = (cf2){ c, -s};
        else if (quad == 1) v = (cf2){-s, -c};
        else if (quad == 2) v = (cf2){-c,  s};
        else                v = (cf2){ s,  c};
        Tw[k] = v;
        return;
    }

    const float* src;
    int nre;
    if (sig < 64)      { src = xi   + sig * L_LEN;         nre = L_LEN; }
    else if (sig < 66) { src = w    + (sig - 64) * L_LEN;  nre = L_LEN; }
    else               { src = tmpl + (sig - 66) * KT_LEN; nre = KT_LEN; }
    const bool isW = (sig >= 64 && sig < 66);
    const int nc = nre >> 1;
    const float4* s4 = (const float4*)src;
    const int g0 = tid ^ ((tid >> 4) & 15);
    #pragma unroll
    for (int m = 0; m < 4; ++m) {
        const int u = 2*tid + 2048*m;
        float4 vv = (u < nc) ? s4[tid + 1024*m] : make_float4(0.f, 0.f, 0.f, 0.f);
        ((float4*)A)[g0 + 1024*m] = vv;
    }
    __syncthreads();

    {   // stage 1: stride 1024, w1 = W_8192^tid
        int idx[8]; const int b0 = swz(tid);
        #pragma unroll
        for (int n = 0; n < 8; ++n) idx[n] = b0 + 1024*n;
        float sn, cs; __sincosf(-PI_F * (float)(2*tid) / 8192.f, &sn, &cs);
        butterfly8<-1>(A, idx, (cf2){cs, sn});
    }
    __syncthreads();
    {   // stage 2: stride 128, w1 = W_1024^j
        const int blk = tid >> 7, j = tid & 127, jb = blk*1024;
        const int jsw = j ^ (((j >> 5) & 3) << 1);
        int idx[8];
        #pragma unroll
        for (int n = 0; n < 8; ++n) idx[n] = jb + 128*n + (jsw ^ ((n & 3) << 3));
        float sn, cs; __sincosf(-PI_F * (float)(16*j) / 8192.f, &sn, &cs);
        butterfly8<-1>(A, idx, (cf2){cs, sn});
    }
    __syncthreads();
    {   // stage 3: stride 16, w1 = W_128^j
        const int blk = tid >> 4, j = tid & 15;
        const int base = blk*128 + j, bx = (blk & 3) << 3;
        int idx[8];
        #pragma unroll
        for (int n = 0; n < 8; ++n) idx[n] = (base + 16*n) ^ bx ^ ((n >> 1) << 1);
        float sn, cs; __sincosf(-PI_F * (float)(128*j) / 8192.f, &sn, &cs);
        butterfly8<-1>(A, idx, (cf2){cs, sn});
    }
    __syncthreads();
    {   // stage 4: stride 2, w1 = W_16^j (constant)
        const int blk = tid >> 1, j = tid & 1;
        const int Xa = ((blk >> 1) & 15) << 1;
        const int base = ((blk << 4) | j) ^ (Xa & 16);
        const int xv = Xa & 14;
        int idx[8];
        #pragma unroll
        for (int n = 0; n < 8; ++n) idx[n] = base + ((2*n) ^ xv);
        cf2 w1 = j ? (cf2){C8, -S8} : (cf2){1.f, 0.f};
        butterfly8<-1>(A, idx, w1);
    }
    __syncthreads();
    // Final radix-2 (stride 1, no twiddle), b128 in-place.
    #pragma unroll
    for (int m = 0; m < 4; ++m) {
        float4 pq = ((float4*)A)[g0 + 1024*m];
        ((float4*)A)[g0 + 1024*m] = make_float4(pq.x + pq.z, pq.y + pq.w,
                                                pq.x - pq.z, pq.y - pq.w);
    }
    __syncthreads();

    // Untangle packed result to X[f], f = 0..M, parity-split output (R19).
    cf2* oute = spec + (size_t)sig * SPEC_STRIDE;
    cf2* outp = (tid & 1) ? (oute + OOFF) : oute;
    const int sbase = tid >> 1;
    #pragma unroll
    for (int m = 0; m < 8; ++m) {
        const int f = tid + 1024*m;
        const int fb = (M_LEN - f) & (M_LEN - 1);
        cf2 Za = A[swz(pos8(f))];
        cf2 Zb = A[swz(pos8(fb))];
        cf2 E = (cf2){0.5f*(Za.x + Zb.x), 0.5f*(Za.y - Zb.y)};
        cf2 D = (cf2){Za.x - Zb.x, Za.y + Zb.y};
        cf2 O = (cf2){0.5f*D.y, -0.5f*D.x};
        float sn, cs;
        __sincosf(-PI_F * (float)f / 8192.f, &sn, &cs);
        cf2 val = E + (cf2){cs*O.x - sn*O.y, cs*O.y + sn*O.x};
        if (isW) {   // V(f) = conj(W(f)) * e^{-i pi k/8192}, k exact int mod
            const int k = (4094 * f) & (L_LEN - 1);
            float psn, pcs; __sincosf(-PI_F * (float)k / 8192.f, &psn, &pcs);
            val = cmul((cf2){val.x, -val.y}, (cf2){pcs, psn});
        }
        outp[sbase + 512*m] = val;
    }
    if (tid == 0) {   // f = 8192 -> even slot 4096
        cf2 Za = A[swz(0)];
        cf2 val = (cf2){Za.x - Za.y, 0.f};
        if (isW) {   // k(8192) = 8192 -> phase = (-1, 0)
            val = (cf2){-val.x, 0.f};
        }
        oute[4096] = val;
    }
}

// ---------------------------------------------------------------------------
// Kernel 1b (R16/R18): XV = X*V, in-place, parity-split layout.
// Even region: float4 [0,2048) + scalar slot 4096; odd: float4 [2056,4104).
// ---------------------------------------------------------------------------
__global__ __launch_bounds__(1024)
void xv_kernel(cf2* __restrict__ spec) {
    const int bc = blockIdx.x;          // 0..63 = b*2 + c
    cf2* Xs = spec + (size_t)bc * SPEC_STRIDE;
    const cf2* Vs = spec + (size_t)(64 + (bc & 1)) * SPEC_STRIDE;
    const int tid = threadIdx.x;
    float4* X4 = (float4*)Xs;
    const float4* V4 = (const float4*)Vs;
    #pragma unroll
    for (int m = 0; m < 2; ++m) {
        const int p = tid + 1024*m;     // even region float4 [0,2048)
        float4 xv = X4[p], vv = V4[p];
        cf2 a = cmul((cf2){xv.x, xv.y}, (cf2){vv.x, vv.y});
        cf2 b = cmul((cf2){xv.z, xv.w}, (cf2){vv.z, vv.w});
        X4[p] = make_float4(a.x, a.y, b.x, b.y);
    }
    #pragma unroll
    for (int m = 0; m < 2; ++m) {
        const int p = 2056 + tid + 1024*m;   // odd region float4
        float4 xv = X4[p], vv = V4[p];
        cf2 a = cmul((cf2){xv.x, xv.y}, (cf2){vv.x, vv.y});
        cf2 b = cmul((cf2){xv.z, xv.w}, (cf2){vv.z, vv.w});
        X4[p] = make_float4(a.x, a.y, b.x, b.y);
    }
    if (tid == 0) Xs[4096] = cmul(Xs[4096], Vs[4096]);   // f = 8192
}

// ---------------------------------------------------------------------------
// Kernel 2 (R15+R16+R18): product (XV * conj(H), parity-split reads) +
// Hermitian pack + FIRST radix-2 stage fused in registers. Then 16,16,16
// stages on the two 4096-halves; stride-1 last stage is read-only + max.
// Z' carries 2x (0.5 dropped) -> divide by 2*M*hh.
// Slot map: f even -> Xe[f>>1]; f odd -> Xo[f>>1].
// ---------------------------------------------------------------------------
__global__ __launch_bounds__(NTI, 4)
void inv_fft_kernel(const cf2* __restrict__ spec, const cf2* __restrict__ T,
                    const float* __restrict__ hh, float* __restrict__ zarr) {
    __shared__ __attribute__((aligned(16))) cf2 A[M_LEN];   // 64 KB
    const int idx0 = blockIdx.x;
    const int c = idx0 & 1;
    const int n = (idx0 >> 1) % NTPL;
    const int b = idx0 / (2 * NTPL);
    const int tid = threadIdx.x;

    const cf2* Xe = spec + (size_t)(b*2 + c)      * SPEC_STRIDE;   // = XV even
    const cf2* He = spec + (size_t)(66 + n*2 + c) * SPEC_STRIDE;
    const cf2* Xo = Xe + OOFF;
    const cf2* Ho = He + OOFF;
    const float4* T4 = (const float4*)T;

    #pragma unroll
    for (int m = 0; m < 2; ++m) {
        const int tp = tid + 512*m;
        // f0 = 2tp (even), f1 = 2tp+1 (odd)
        cf2 PA0 = cmulc(Xe[tp],        He[tp]);          // X[f0]
        cf2 PA1 = cmulc(Xo[tp],        Ho[tp]);          // X[f1]
        cf2 QB0 = cmulc(Xe[2048 + tp], He[2048 + tp]);   // X[4096+f0]
        cf2 QB1 = cmulc(Xo[2048 + tp], Ho[2048 + tp]);   // X[4096+f1]
        cf2 PB0 = cmulc(Xe[2048 - tp], He[2048 - tp]);   // X[4096-f0]
        cf2 PB1 = cmulc(Xo[2047 - tp], Ho[2047 - tp]);   // X[4096-f1]
        cf2 QA0 = cmulc(Xe[4096 - tp], He[4096 - tp]);   // X[8192-f0]
        cf2 QA1 = cmulc(Xo[4095 - tp], Ho[4095 - tp]);   // X[8192-f1]
        const int f0 = 2*tp;
        float4 tf4 = T4[tp];            // T[f0], T[f1]
        float4 t2a = T4[2*tp];          // T[2f0] in .xy
        float4 t2b = T4[2*tp + 1];      // T[2f1] in .xy
        cf2 Tf0 = (cf2){tf4.x, tf4.y}, Tf1 = (cf2){tf4.z, tf4.w};
        cf2 T20 = (cf2){t2a.x, t2a.y}, T21 = (cf2){t2b.x, t2b.y};
        // --- f0 ---
        cf2 SpA0 = pk_addch(PA0, QA0), SmA0 = pk_subcl(PA0, QA0);
        cf2 RA0 = cmulca(Tf0, SmA0);
        cf2 ZA1_0 = pk_compose1(SpA0, RA0);     // Z'[f0]
        cf2 ZA2_0 = pk_compose2(SpA0, RA0);     // Z'[8192-f0]
        cf2 tB0 = (cf2){-Tf0.y, -Tf0.x};        // T[4096-f0]
        cf2 SpB0 = pk_addch(PB0, QB0), SmB0 = pk_subcl(PB0, QB0);
        cf2 RB0 = cmulca(tB0, SmB0);
        cf2 ZB1_0 = pk_compose1(SpB0, RB0);     // Z'[4096-f0]
        cf2 ZB2_0 = pk_compose2(SpB0, RB0);     // Z'[4096+f0]
        cf2 top0 = ZA1_0 + ZB2_0;
        cf2 bot0 = cmulca(T20, ZA1_0 - ZB2_0);
        // --- f1 ---
        cf2 SpA1 = pk_addch(PA1, QA1), SmA1 = pk_subcl(PA1, QA1);
        cf2 RA1 = cmulca(Tf1, SmA1);
        cf2 ZA1_1 = pk_compose1(SpA1, RA1);
        cf2 ZA2_1 = pk_compose2(SpA1, RA1);
        cf2 tB1 = (cf2){-Tf1.y, -Tf1.x};
        cf2 SpB1 = pk_addch(PB1, QB1), SmB1 = pk_subcl(PB1, QB1);
        cf2 RB1 = cmulca(tB1, SmB1);
        cf2 ZB1_1 = pk_compose1(SpB1, RB1);
        cf2 ZB2_1 = pk_compose2(SpB1, RB1);
        cf2 top1 = ZA1_1 + ZB2_1;
        cf2 bot1 = cmulca(T21, ZA1_1 - ZB2_1);
        // coalesced swizzled float4 writes for the fwd side
        const int gt = tp ^ ((tp >> 4) & 15);
        ((float4*)A)[gt]        = make_float4(top0.x, top0.y, top1.x, top1.y);
        ((float4*)A)[2048 + gt] = make_float4(bot0.x, bot0.y, bot1.x, bot1.y);
        // rev-side butterflies (skip f0 == 0: its pair (4096,8192) is invalid;
        // the fwd butterfly above already used the correct self-paired Z'[4096])
        if (tp > 0) {
            cf2 tr0 = ZB1_0 + ZA2_0;
            cf2 dr0 = cmul(ZB1_0 - ZA2_0, T20);
            A[swz(4096 - f0)] = tr0;
            A[swz(8192 - f0)] = -dr0;
        }
        cf2 tr1 = ZB1_1 + ZA2_1;
        cf2 dr1 = cmul(ZB1_1 - ZA2_1, T21);
        A[swz(4096 - f0 - 1)] = tr1;
        A[swz(8192 - f0 - 1)] = -dr1;
    }
    if (tid == 0) {   // f = 2048 butterfly (2048, 6144), Wi^2048 = +i
        cf2 P = cmulc(Xe[1024], He[1024]);   // X[2048]
        cf2 Q = cmulc(Xe[3072], He[3072]);   // X[6144]
        cf2 Tc = (cf2){R2_F, -R2_F};         // T[2048]
        cf2 Sp = pk_addch(P, Q), Sm = pk_subcl(P, Q);
        cf2 R = cmulca(Tc, Sm);
        cf2 Z1 = pk_compose1(Sp, R), Z2 = pk_compose2(Sp, R);
        cf2 d = Z1 - Z2;
        A[swz(2048)] = Z1 + Z2;
        A[swz(6144)] = (cf2){-d.y, d.x};
    }
    __syncthreads();

    {   // stage 1 of the 4096-halves: stride 256, w1 = conj(T[4j])
        const int h = tid >> 8, j = tid & 255;
        const int Hb = h << 12;
        const int jx = j ^ (((j >> 5) & 7) << 1);
        int idx[16];
        #pragma unroll
        for (int nn = 0; nn < 16; ++nn)
            idx[nn] = Hb + 256*nn + (jx ^ ((nn & 1) << 4));
        butterfly16<+1>(A, idx, ldT<+1>(T, 4*j));
    }
    __syncthreads();
    {   // stage 2: stride 16, w1 = conj(T[64j])
        const int h = tid >> 8, q = (tid >> 4) & 15, j = tid & 15;
        const int base = (h << 12) + (q << 8);
        const int qb = q & 1;
        int idx[16];
        #pragma unroll
        for (int nn = 0; nn < 16; ++nn)
            idx[nn] = base + 16*(nn ^ qb) + (j ^ (((nn >> 1) & 7) << 1));
        butterfly16<+1>(A, idx, ldT<+1>(T, 64*j));
    }
    __syncthreads();

    // stage 3: stride 1, twiddle = W_16^0 = 1 -> read-only dft16 + max.
    float mx = -INFINITY;
    {
        const int bb = 16 * (tid ^ ((tid >> 4) & 1));
        const int m3 = ((tid >> 1) & 7) << 1;
        cf2 x[16];
        #pragma unroll
        for (int e = 0; e < 8; ++e) {
            float4 v = ((const float4*)A)[(bb + ((2*e) ^ m3)) >> 1];
            x[2*e]     = (cf2){v.x, v.y};
            x[2*e + 1] = (cf2){v.z, v.w};
        }
        dft16<+1>(x);
        #pragma unroll
        for (int nn = 0; nn < 16; ++nn)
            mx = fmaxf(mx, fmaxf(x[nn].x, x[nn].y));
    }
    __syncthreads();   // all stage-3 reads done before reusing A as scratch
    for (int off = 32; off > 0; off >>= 1)
        mx = fmaxf(mx, __shfl_xor(mx, off));
    const int lane = tid & 63, wv = tid >> 6;   // 8 waves
    float* redf = (float*)A;
    if (lane == 0) redf[wv] = mx;
    __syncthreads();
    if (tid == 0) {
        float mm = redf[0];
        for (int i = 1; i < NTI/64; ++i) mm = fmaxf(mm, redf[i]);
        zarr[(b*2 + c)*NTPL + n] = mm / (2.f * (float)M_LEN * hh[n*2 + c]);
    }
}

// ---------------------------------------------------------------------------
// Kernel 3: tiny CNN/MLP head. One block per batch element.
// R12: all weights staged in LDS (coalesced), all MAC loops unrolled over
// LDS reads, fc1 parallelized 32 outputs x 8 lanes + shfl_xor tree.
// ---------------------------------------------------------------------------
#define W1_OFF 0        // 16x6 = 96
#define B1_OFF 96       // 16
#define W2_OFF 112      // 32x48 = 1536
#define B2_OFF 1648     // 32
#define W3_OFF 1680     // 32x132 (padded from 128) = 4224
#define B3_OFF 5904     // 32
#define W4_OFF 5936     // 2x32 = 64
#define B4_OFF 6000     // 2
#define WSM_SZ 6002

__global__ __launch_bounds__(256)
void head_kernel(const float* __restrict__ zarr,
                 const float* __restrict__ W1, const float* __restrict__ b1,
                 const float* __restrict__ W2, const float* __restrict__ b2,
                 const float* __restrict__ W3, const float* __restrict__ b3,
                 const float* __restrict__ W4, const float* __restrict__ b4,
                 float* __restrict__ out) {
    __shared__ float wsm[WSM_SZ];
    __shared__ float zl[2*NTPL];
    __shared__ float s1[16*48];
    __shared__ float p1[16*16];
    __shared__ float s2[32*14];
    __shared__ float hflat[128];
    __shared__ float h1[32];
    const int b = blockIdx.x, tid = threadIdx.x;

    for (int i = tid; i < 96;   i += 256) wsm[W1_OFF + i] = W1[i];
    if (tid < 16)                         wsm[B1_OFF + tid] = b1[tid];
    for (int i = tid; i < 1536; i += 256) wsm[W2_OFF + i] = W2[i];
    if (tid < 32)                         wsm[B2_OFF + tid] = b2[tid];
    for (int i = tid; i < 4096; i += 256)
        wsm[W3_OFF + (i >> 7)*132 + (i & 127)] = W3[i];
    if (tid < 32)                         wsm[B3_OFF + tid] = b3[tid];
    if (tid < 64)                         wsm[W4_OFF + tid] = W4[tid];
    if (tid < 2)                          wsm[B4_OFF + tid] = b4[tid];
    for (int i = tid; i < 2*NTPL; i += 256) zl[i] = zarr[b*2*NTPL + i];
    __syncthreads();

    for (int i = tid; i < 16*48; i += 256) {
        const int o = i / 48, t = i % 48;
        float acc = wsm[B1_OFF + o];
        #pragma unroll
        for (int cc = 0; cc < 2; ++cc)
            #pragma unroll
            for (int k = 0; k < 3; ++k)
                acc += zl[cc*NTPL + t + k] * wsm[W1_OFF + o*6 + cc*3 + k];
        s1[i] = 1.f / (1.f + __expf(-acc));
    }
    __syncthreads();
    for (int i = tid; i < 16*16; i += 256) {
        const int o = i / 16, u = i % 16;
        p1[i] = fmaxf(fmaxf(s1[o*48 + 3*u], s1[o*48 + 3*u+1]), s1[o*48 + 3*u+2]);
    }
    __syncthreads();
    for (int i = tid; i < 32*14; i += 256) {
        const int o = i / 14, t = i % 14;
        float acc = wsm[B2_OFF + o];
        #pragma unroll
        for (int cc = 0; cc < 16; ++cc)
            #pragma unroll
            for (int k = 0; k < 3; ++k)
                acc += p1[cc*16 + t + k] * wsm[W2_OFF + o*48 + cc*3 + k];
        s2[o*14 + t] = 1.f / (1.f + __expf(-acc));
    }
    __syncthreads();
    for (int i = tid; i < 128; i += 256) {
        const int o = i / 4, u = i % 4;
        hflat[i] = fmaxf(fmaxf(s2[o*14 + 3*u], s2[o*14 + 3*u+1]), s2[o*14 + 3*u+2]);
    }
    __syncthreads();
    {
        const int o = tid >> 3, lg = tid & 7;
        float acc = 0.f;
        #pragma unroll
        for (int k = 0; k < 16; ++k)
            acc += hflat[lg + 8*k] * wsm[W3_OFF + o*132 + lg + 8*k];
        acc += __shfl_xor(acc, 1);
        acc += __shfl_xor(acc, 2);
        acc += __shfl_xor(acc, 4);
        if (lg == 0) h1[o] = fmaxf(acc + wsm[B3_OFF + o], 0.f);
    }
    __syncthreads();
    if (tid < 64) {
        const int o = tid >> 5, j = tid & 31;
        float p = h1[j] * wsm[W4_OFF + o*32 + j];
        p += __shfl_xor(p, 1);
        p += __shfl_xor(p, 2);
        p += __shfl_xor(p, 4);
        p += __shfl_xor(p, 8);
        p += __shfl_xor(p, 16);
        if (j == 0) out[b*2 + o] = p + wsm[B4_OFF + o];
    }
}

extern "C" void kernel_launch(void* const* d_in, const int* in_sizes, int n_in,
                              void* d_out, int out_size, void* d_ws, size_t ws_size,
                              hipStream_t stream) {
    const float* xi   = (const float*)d_in[0];
    const float* Sw   = (const float*)d_in[1];
    const float* tmpl = (const float*)d_in[2];
    const float* hh   = (const float*)d_in[3];
    const float* W1   = (const float*)d_in[4];
    const float* b1   = (const float*)d_in[5];
    const float* W2   = (const float*)d_in[6];
    const float* b2   = (const float*)d_in[7];
    const float* W3   = (const float*)d_in[8];
    const float* b3   = (const float*)d_in[9];
    const float* W4   = (const float*)d_in[10];
    const float* b4   = (const float*)d_in[11];
    float* out = (float*)d_out;

    cf2* T16  = (cf2*)d_ws;                         // 16384 cf2 = 128 KB
    cf2* spec = T16 + 16384;                        // NSIG * SPEC_STRIDE cf2
    float* zarr = (float*)(spec + (size_t)NSIG * SPEC_STRIDE);

    // fwd grid: NSIG FFT blocks + 16 twiddle-writer blocks (1024 thr).
    fwd_fft_kernel<<<dim3(NSIG + 16), dim3(NTF), 0, stream>>>(xi, Sw, tmpl, T16, spec);
    xv_kernel<<<dim3(64), dim3(1024), 0, stream>>>(spec);
    inv_fft_kernel<<<dim3(BB * NTPL * 2), dim3(NTI), 0, stream>>>(spec, T16, hh, zarr);
    head_kernel<<<dim3(BB), dim3(256), 0, stream>>>(zarr, W1, b1, W2, b2, W3, b3, W4, b4, out);
}